// Round 10
// baseline (37415.173 us; speedup 1.0000x reference)
//
#include <hip/hip_runtime.h>
#include <cstdint>
#include <cstddef>

// ---------------------------------------------------------------------------
// Parareal neural-ODE (MSZero_13761075216509)
// f(x) = tanh(x@W1 + b1) @ W2 ; fp32 via bf16 hi/lo 3-term split MFMA.
// R10: 128^2 GEMM -> m97-exact occupancy structure: single-buffered 32KB LDS
//      (XOR-slot conflict-free layout kept), launch_bounds(256,3) -> 3
//      blocks/CU; stage->sync->compute->sync with wave-level overlap doing
//      the latency hiding (m114/m139: dbuf adds nothing at 128^2, the third
//      block does). Dispatch structure identical to R9 (36.8ms).
// ---------------------------------------------------------------------------

typedef __attribute__((ext_vector_type(4))) float f32x4;
typedef __attribute__((ext_vector_type(8))) short s16x8;
typedef __attribute__((ext_vector_type(4))) unsigned short u16x4;

#define DEV __device__ __forceinline__

DEV unsigned short f2bf(float x) {
  union { float f; uint32_t u; } v; v.f = x;
  uint32_t r = v.u + 0x7FFFu + ((v.u >> 16) & 1u);   // RNE
  return (unsigned short)(r >> 16);
}
DEV float bf2f(unsigned short h) {
  union { uint32_t u; float f; } v; v.u = ((uint32_t)h) << 16; return v.f;
}
DEV void split2(float x, unsigned short &h, unsigned short &l) {
  h = f2bf(x);
  l = f2bf(x - bf2f(h));
}
DEV float fast_tanh(float z) {
  return 1.f - 2.f / (__expf(2.f * z) + 1.f);
}
DEV void gload16(const unsigned short* g, unsigned short* l) {
  __builtin_amdgcn_global_load_lds(
      (const __attribute__((address_space(1))) void*)g,
      (__attribute__((address_space(3))) void*)l, 16, 0, 0);
}

// ---------------------------------------------------------------------------
// 128x128 GEMM, m97 occupancy structure: C[M,N] = A[M,K]*B[K,N]; A hi/lo bf16
// [M][K], B pre-transposed hi/lo bf16 [N][K]. Ah*Bh + Ah*Bl + Al*Bh, fp32 acc.
// LDS: ONE 16KB tile per operand, [128 rows][8 slots x 16B] (slots 0-3 hi,
// 4-7 lo), phys slot = src ^ (row&7) -> conflict-free ds_read_b128.
// Loop: STAGE(kt) -> sync -> compute -> sync. 32KB LDS + <=170 VGPR -> 3
// blocks/CU; co-resident blocks hide the stage latency (m114).
// EPI=1: v=tanh(acc+bias[col]) -> Oh/Ol bf16
// EPI=3: rk-update: a=(add?ACC:X)+a1*sdt*acc -> ACC ; xt=X+a2*sdt*acc -> Oh/Ol
// EPI=4: axpy-update: v=Xin+(a1+a2*sdt)*acc -> Xout fp32 + Oh/Ol split
// ---------------------------------------------------------------------------
template<int EPI>
__global__ __launch_bounds__(256, 3) void gemm_k(
    const unsigned short* __restrict__ Ah, const unsigned short* __restrict__ Al,
    const unsigned short* __restrict__ Bh, const unsigned short* __restrict__ Bl,
    const float* __restrict__ bias,
    unsigned short* __restrict__ Oh, unsigned short* __restrict__ Ol,
    const float* __restrict__ Xin,
    float* __restrict__ ACCb,
    float* __restrict__ Xout,
    const float* __restrict__ tspan,
    float a1, float a2, int accAdd,
    int M, int N, int K, int KS)
{
  __shared__ unsigned short sA[128 * 64];   // 16 KB
  __shared__ unsigned short sB[128 * 64];   // 16 KB
  const int tid = threadIdx.x;
  const int w = tid >> 6, l = tid & 63;
  const int m0 = blockIdx.y * 128, n0 = blockIdx.x * 128;
  const int wm = (w >> 1) * 64, wn = (w & 1) * 64;

  f32x4 acc[4][4];
#pragma unroll
  for (int a = 0; a < 4; ++a)
#pragma unroll
    for (int b = 0; b < 4; ++b) acc[a][b] = (f32x4){0.f, 0.f, 0.f, 0.f};

  // staging: call j of wave w writes bytes [w*1024 + j*4096 + lane*16)
  // -> row j*32 + w*8 + (l>>3), phys slot l&7; phys slot holds src ^ (row&7)
  const int rsub = w * 8 + (l >> 3);
  const int ssrc = (l & 7) ^ (l >> 3);
  const int shalf = ssrc >> 2;
  const int schunk = ssrc & 3;
  const unsigned short* gA = (shalf ? Al : Ah) + (size_t)(m0 + rsub) * K + schunk * 8;
  const unsigned short* gB = (shalf ? Bl : Bh) + (size_t)(n0 + rsub) * K + schunk * 8;
  const size_t gstep = (size_t)32 * (size_t)K;
  const int db = w * 512;

  // fragment-read: A[R0+(l&15)][k=(l>>4)*8..]; phys slot = (h*4+(l>>4))^(l&7)
  const int arow = (l & 15);
  const int slotH = ((l >> 4)) ^ (l & 7);
  const int slotL = (4 + (l >> 4)) ^ (l & 7);

  const int nk = KS >> 5;

  for (int kt = 0; kt < nk; ++kt) {
    const size_t ko = (size_t)kt * 32;
#pragma unroll
    for (int j = 0; j < 4; ++j) {
      gload16(gA + ko + (size_t)j * gstep, &sA[db + j * 2048]);
      gload16(gB + ko + (size_t)j * gstep, &sB[db + j * 2048]);
    }
    __syncthreads();   // drains vmcnt -> tiles ready

    // B fragments resident; A fragments streamed per mi (VGPR budget)
    s16x8 bfh[4], bfl[4];
#pragma unroll
    for (int ni = 0; ni < 4; ++ni) {
      const int rb = (wn + ni * 16 + arow) * 64;
      bfh[ni] = *(const s16x8*)&sB[rb + slotH * 8];
      bfl[ni] = *(const s16x8*)&sB[rb + slotL * 8];
    }
#pragma unroll
    for (int mi = 0; mi < 4; ++mi) {
      const int rb = (wm + mi * 16 + arow) * 64;
      const s16x8 afh = *(const s16x8*)&sA[rb + slotH * 8];
      const s16x8 afl = *(const s16x8*)&sA[rb + slotL * 8];
#pragma unroll
      for (int ni = 0; ni < 4; ++ni) {
        acc[mi][ni] = __builtin_amdgcn_mfma_f32_16x16x32_bf16(afh, bfh[ni], acc[mi][ni], 0, 0, 0);
        acc[mi][ni] = __builtin_amdgcn_mfma_f32_16x16x32_bf16(afh, bfl[ni], acc[mi][ni], 0, 0, 0);
        acc[mi][ni] = __builtin_amdgcn_mfma_f32_16x16x32_bf16(afl, bfh[ni], acc[mi][ni], 0, 0, 0);
      }
    }
    __syncthreads();   // all reads done before next-iter overwrite
  }

  // epilogue: row = wm+mi*16+(l>>4)*4+j, col = wn+ni*16+(l&15)
  const int colb = n0 + wn + (l & 15);
  const int rowb = m0 + wm + (l >> 4) * 4;
  const float sdt = (EPI >= 3) ? (tspan[1] - tspan[0]) * (1.0f / 7.0f) : 0.f;

  if (EPI == 1) {
#pragma unroll
    for (int mi = 0; mi < 4; ++mi)
#pragma unroll
      for (int ni = 0; ni < 4; ++ni) {
        const int col = colb + ni * 16;
        const float bc = bias[col];
#pragma unroll
        for (int j = 0; j < 4; ++j) {
          const size_t idx = (size_t)(rowb + mi * 16 + j) * N + col;
          const float v = fast_tanh(acc[mi][ni][j] + bc);
          unsigned short hh, ll; split2(v, hh, ll);
          Oh[idx] = hh; Ol[idx] = ll;
        }
      }
  } else if (EPI == 3) {
    const float c1 = a1 * sdt, c2 = a2 * sdt;
#pragma unroll
    for (int mi = 0; mi < 4; ++mi)
#pragma unroll
      for (int ni = 0; ni < 4; ++ni) {
        const int col = colb + ni * 16;
#pragma unroll
        for (int j = 0; j < 4; ++j) {
          const size_t idx = (size_t)(rowb + mi * 16 + j) * N + col;
          const float f = acc[mi][ni][j];
          const float x = Xin[idx];
          const float a = (accAdd ? ACCb[idx] : x) + c1 * f;
          ACCb[idx] = a;
          const float xt = x + c2 * f;
          unsigned short hh, ll; split2(xt, hh, ll);
          Oh[idx] = hh; Ol[idx] = ll;
        }
      }
  } else {  // EPI == 4
    const float coef = a1 + a2 * sdt;
#pragma unroll
    for (int mi = 0; mi < 4; ++mi)
#pragma unroll
      for (int ni = 0; ni < 4; ++ni) {
        const int col = colb + ni * 16;
#pragma unroll
        for (int j = 0; j < 4; ++j) {
          const size_t idx = (size_t)(rowb + mi * 16 + j) * N + col;
          const float v = Xin[idx] + coef * acc[mi][ni][j];
          Xout[idx] = v;
          unsigned short hh, ll; split2(v, hh, ll);
          Oh[idx] = hh; Ol[idx] = ll;
        }
      }
  }
}

// ---------------------------------------------------------------------------
// 64x64 GEMM for the sequential phase (R9, unchanged - seq is dispatch-bound)
// EPI=1: tanh(acc+bias)->Oh/Ol.  EPI=2: Part + blockIdx.z*M*N partial.
// ---------------------------------------------------------------------------
template<int EPI>
__global__ __launch_bounds__(256, 2) void gemm64_k(
    const unsigned short* __restrict__ Ah, const unsigned short* __restrict__ Al,
    const unsigned short* __restrict__ Bh, const unsigned short* __restrict__ Bl,
    const float* __restrict__ bias,
    float* __restrict__ Part,
    unsigned short* __restrict__ Oh, unsigned short* __restrict__ Ol,
    int M, int N, int K, int KS)
{
  __shared__ unsigned short sA[2][64 * 64];
  __shared__ unsigned short sB[2][64 * 64];
  const int tid = threadIdx.x;
  const int w = tid >> 6, l = tid & 63;
  const int m0 = blockIdx.y * 64, n0 = blockIdx.x * 64;
  const size_t kbeg = (size_t)blockIdx.z * (size_t)KS;
  const int wm = (w >> 1) * 32, wn = (w & 1) * 32;

  f32x4 acc[2][2];
#pragma unroll
  for (int a = 0; a < 2; ++a)
#pragma unroll
    for (int b = 0; b < 2; ++b) acc[a][b] = (f32x4){0.f, 0.f, 0.f, 0.f};

  const int rsub = w * 8 + (l >> 3);
  const int ssrc = (l & 7) ^ (l >> 3);
  const int shalf = ssrc >> 2;
  const int schunk = ssrc & 3;
  const unsigned short* gA = (shalf ? Al : Ah) + (size_t)(m0 + rsub) * K + kbeg + schunk * 8;
  const unsigned short* gB = (shalf ? Bl : Bh) + (size_t)(n0 + rsub) * K + kbeg + schunk * 8;
  const size_t gstep = (size_t)32 * (size_t)K;
  const int db = w * 512;

  const int arow = (l & 15);
  const int slotH = ((l >> 4)) ^ (l & 7);
  const int slotL = (4 + (l >> 4)) ^ (l & 7);

  const int nk = KS >> 5;

  auto STAGE = [&](int buf, int kt) {
    const size_t ko = (size_t)kt * 32;
    unsigned short* da = &sA[buf][db];
    unsigned short* dbp = &sB[buf][db];
#pragma unroll
    for (int j = 0; j < 2; ++j) {
      gload16(gA + ko + (size_t)j * gstep, da + j * 2048);
      gload16(gB + ko + (size_t)j * gstep, dbp + j * 2048);
    }
  };

  STAGE(0, 0);
  __syncthreads();
  int cur = 0;

  for (int kt = 0; kt < nk; ++kt) {
    if (kt + 1 < nk) STAGE(cur ^ 1, kt + 1);
    const unsigned short* pa = &sA[cur][0];
    const unsigned short* pb = &sB[cur][0];
    s16x8 afh[2], afl[2], bfh[2], bfl[2];
#pragma unroll
    for (int mi = 0; mi < 2; ++mi) {
      const int rb = (wm + mi * 16 + arow) * 64;
      afh[mi] = *(const s16x8*)&pa[rb + slotH * 8];
      afl[mi] = *(const s16x8*)&pa[rb + slotL * 8];
    }
#pragma unroll
    for (int ni = 0; ni < 2; ++ni) {
      const int rb = (wn + ni * 16 + arow) * 64;
      bfh[ni] = *(const s16x8*)&pb[rb + slotH * 8];
      bfl[ni] = *(const s16x8*)&pb[rb + slotL * 8];
    }
#pragma unroll
    for (int mi = 0; mi < 2; ++mi)
#pragma unroll
      for (int ni = 0; ni < 2; ++ni) {
        acc[mi][ni] = __builtin_amdgcn_mfma_f32_16x16x32_bf16(afh[mi], bfh[ni], acc[mi][ni], 0, 0, 0);
        acc[mi][ni] = __builtin_amdgcn_mfma_f32_16x16x32_bf16(afh[mi], bfl[ni], acc[mi][ni], 0, 0, 0);
        acc[mi][ni] = __builtin_amdgcn_mfma_f32_16x16x32_bf16(afl[mi], bfh[ni], acc[mi][ni], 0, 0, 0);
      }
    __syncthreads();
    cur ^= 1;
  }

  const int colb = n0 + wn + (l & 15);
  const int rowb = m0 + wm + (l >> 4) * 4;

  if (EPI == 1) {
#pragma unroll
    for (int mi = 0; mi < 2; ++mi)
#pragma unroll
      for (int ni = 0; ni < 2; ++ni) {
        const int col = colb + ni * 16;
        const float bc = bias[col];
#pragma unroll
        for (int j = 0; j < 4; ++j) {
          const size_t idx = (size_t)(rowb + mi * 16 + j) * N + col;
          const float v = fast_tanh(acc[mi][ni][j] + bc);
          unsigned short hh, ll; split2(v, hh, ll);
          Oh[idx] = hh; Ol[idx] = ll;
        }
      }
  } else {
    float* dst = Part + (size_t)blockIdx.z * (size_t)M * N;
#pragma unroll
    for (int mi = 0; mi < 2; ++mi)
#pragma unroll
      for (int ni = 0; ni < 2; ++ni) {
        const int col = colb + ni * 16;
#pragma unroll
        for (int j = 0; j < 4; ++j)
          dst[(size_t)(rowb + mi * 16 + j) * N + col] = acc[mi][ni][j];
      }
  }
}

// ---------------------------------------------------------------------------
// seq GEMM2 finish: F = sum_z Part[z]; E = X + sdt*F; [Eout=E];
// v = E [+ Dv]; X = v (+ hi/lo split); [Bout=v]
// ---------------------------------------------------------------------------
__global__ void reduce_axpy_k(const float* __restrict__ part, int S, int MN4,
    const float* __restrict__ tspan,
    float* __restrict__ Xf, unsigned short* __restrict__ Xh, unsigned short* __restrict__ Xl,
    const float* __restrict__ Dv, float* __restrict__ Bout, float* __restrict__ Eout)
{
  const int i = blockIdx.x * blockDim.x + threadIdx.x;
  if (i >= MN4) return;
  const float sdt = (tspan[1] - tspan[0]) * (1.0f / 7.0f);
  const size_t MN = (size_t)MN4 * 4;
  const size_t o = 4 * (size_t)i;
  f32x4 s = *(const f32x4*)(part + o);
  for (int z = 1; z < S; ++z) s += *(const f32x4*)(part + (size_t)z * MN + o);
  f32x4 e = *(const f32x4*)(Xf + o) + sdt * s;
  if (Eout) *(f32x4*)(Eout + o) = e;
  f32x4 v = e;
  if (Dv) v += *(const f32x4*)(Dv + o);
  *(f32x4*)(Xf + o) = v;
  u16x4 hh, ll;
#pragma unroll
  for (int j = 0; j < 4; ++j) { unsigned short h_, l_; split2(v[j], h_, l_); hh[j] = h_; ll[j] = l_; }
  *(u16x4*)(Xh + o) = hh;
  *(u16x4*)(Xl + o) = ll;
  if (Bout) *(f32x4*)(Bout + o) = v;
}

// ---------------------------------------------------------------------------
__global__ void axpy_split_k(
    float* __restrict__ dstF, unsigned short* __restrict__ dstH,
    unsigned short* __restrict__ dstL,
    const float* __restrict__ A, const float* __restrict__ Fv,
    float coef, int n4)
{
  for (int i = blockIdx.x * blockDim.x + threadIdx.x; i < n4;
       i += gridDim.x * blockDim.x) {
    const size_t o = 4 * (size_t)i;
    const f32x4 a = *(const f32x4*)(A + o);
    const f32x4 f = *(const f32x4*)(Fv + o);
    f32x4 v = a + coef * f;
    *(f32x4*)(dstF + o) = v;
    if (dstH) {
      u16x4 hh, ll;
#pragma unroll
      for (int j = 0; j < 4; ++j) { unsigned short h_, l_; split2(v[j], h_, l_); hh[j] = h_; ll[j] = l_; }
      *(u16x4*)(dstH + o) = hh;
      *(u16x4*)(dstL + o) = ll;
    }
  }
}

// ---------------------------------------------------------------------------
__global__ void transpose_split_k(const float* __restrict__ W,
                                  unsigned short* __restrict__ Th,
                                  unsigned short* __restrict__ Tl,
                                  int K, int N)
{
  __shared__ float t[32][33];
  const int tx = threadIdx.x & 31, ty = threadIdx.x >> 5;
  const int n0 = blockIdx.x * 32, k0 = blockIdx.y * 32;
#pragma unroll
  for (int r = 0; r < 4; ++r) {
    const int row = ty + r * 8;
    t[row][tx] = W[(size_t)(k0 + row) * N + n0 + tx];
  }
  __syncthreads();
#pragma unroll
  for (int r = 0; r < 4; ++r) {
    const int row = ty + r * 8;
    const float v = t[tx][row];
    unsigned short hh, ll; split2(v, hh, ll);
    const size_t idx = (size_t)(n0 + row) * K + k0 + tx;
    Th[idx] = hh; Tl[idx] = ll;
  }
}

// ---------------------------------------------------------------------------
extern "C" void kernel_launch(void* const* d_in, const int* in_sizes, int n_in,
                              void* d_out, int out_size, void* d_ws, size_t ws_size,
                              hipStream_t stream)
{
  const float* Bin   = (const float*)d_in[0];
  const float* tspan = (const float*)d_in[1];
  const float* W1    = (const float*)d_in[2];
  const float* b1    = (const float*)d_in[3];
  const float* W2    = (const float*)d_in[4];

  const int n = in_sizes[1];                 // 16
  const int h = in_sizes[3];                 // 4096
  const int d = in_sizes[2] / h;             // 1024
  const int batch = in_sizes[0] / (n * d);   // 256
  const int S = 7;                           // fine_steps-1
  const int MAXIT = 2;
  const size_t NB = (size_t)batch * d;

  float* Bw = (float*)d_out;

  uint8_t* wsb = (uint8_t*)d_ws;
  size_t off = 0;
  auto carve = [&](size_t bytes) -> void* {
    off = (off + 255) & ~(size_t)255;
    void* p = wsb + off; off += bytes; return p;
  };

  const size_t WH = (size_t)d * h;
  unsigned short* W1Th = (unsigned short*)carve(WH * 2);
  unsigned short* W1Tl = (unsigned short*)carve(WH * 2);
  unsigned short* W2Th = (unsigned short*)carve(WH * 2);
  unsigned short* W2Tl = (unsigned short*)carve(WH * 2);
  float* Dbuf = (float*)carve((size_t)(n - 1) * NB * 4);
  float* Eb   = (float*)carve((size_t)n * NB * 4);

  // seq GEMM2 partials: z=4 x batch x d (4.2 MB)
  const int SPL2 = 4;
  float* Part = (float*)carve((size_t)SPL2 * NB * 4);

  // per node: Cst4 + Csh2 + Csl2 + Xf4 + Xh2 + Xl2 + ACC4 (XT aliases Cs) + Y4
  const size_t per_node = NB * 20 + (size_t)batch * h * 4;
  int c;
  {
    size_t remb = ws_size > off + (1u << 20) ? ws_size - off - (1u << 20) : 0;
    c = (int)(remb / per_node);
    if (c < 1) c = 1;
    if (c > n - 1) c = n - 1;
  }
  const size_t CE = (size_t)c * NB;
  float*          Cst = (float*)carve(CE * 4);
  unsigned short* Csh = (unsigned short*)carve(CE * 2);
  unsigned short* Csl = (unsigned short*)carve(CE * 2);
  float*          Xf  = (float*)carve(CE * 4);
  unsigned short* Xh  = (unsigned short*)carve(CE * 2);
  unsigned short* Xl  = (unsigned short*)carve(CE * 2);
  float*          ACC = (float*)carve(CE * 4);
  unsigned short* Yh  = (unsigned short*)carve((size_t)c * batch * h * 2);
  unsigned short* Yl  = (unsigned short*)carve((size_t)c * batch * h * 2);
  unsigned short* XTh = Csh;   // time-disjoint with coarse sweep
  unsigned short* XTl = Csl;

  auto ewg = [](size_t n4) -> int {
    size_t g = (n4 + 255) / 256;
    if (g > 2048) g = 2048; if (g < 1) g = 1;
    return (int)g;
  };
  auto axpy = [&](float* dF, unsigned short* dH, unsigned short* dL,
                  const float* A, const float* Fv, float coef, size_t ne) {
    const int n4 = (int)(ne / 4);
    axpy_split_k<<<ewg(n4), 256, 0, stream>>>(dF, dH, dL, A, Fv, coef, n4);
  };
  // vect g1: 128^2, fused tanh+split epilogue
  auto g1 = [&](const unsigned short* xh, const unsigned short* xl, int M) {
    gemm_k<1><<<dim3(h / 128, M / 128, 1), 256, 0, stream>>>(
        xh, xl, W1Th, W1Tl, b1, Yh, Yl,
        nullptr, nullptr, nullptr, tspan, 0.f, 0.f, 0, M, h, d, d);
  };
  auto g2rk = [&](int M, float a1, float a2, int add) {
    gemm_k<3><<<dim3(d / 128, M / 128, 1), 256, 0, stream>>>(
        Yh, Yl, W2Th, W2Tl, nullptr, XTh, XTl,
        Xf, ACC, nullptr, tspan, a1, a2, add, M, d, h, h);
  };
  auto g2ax = [&](int M, float* dF, unsigned short* dH, unsigned short* dL,
                  const float* Xin, float a1, float a2) {
    gemm_k<4><<<dim3(d / 128, M / 128, 1), 256, 0, stream>>>(
        Yh, Yl, W2Th, W2Tl, nullptr, dH, dL,
        Xin, nullptr, dF, tspan, a1, a2, 0, M, d, h, h);
  };

  // ---- prep ---------------------------------------------------------------
  hipMemcpyAsync(Bw, Bin, (size_t)n * NB * 4, hipMemcpyDeviceToDevice, stream);
  transpose_split_k<<<dim3(h / 32, d / 32), 256, 0, stream>>>(W1, W1Th, W1Tl, d, h);
  transpose_split_k<<<dim3(d / 32, h / 32), 256, 0, stream>>>(W2, W2Th, W2Tl, h, d);

  const int MN4d = (int)(NB / 4);

  // ---- Parareal outer loop ------------------------------------------------
  for (int i = 1; i <= MAXIT + 1; ++i) {
    const int rem = n - i;

    for (int base = 0; base < rem; base += c) {
      const int cc = (rem - base) < c ? (rem - base) : c;
      const int M = cc * batch;
      const size_t ne = (size_t)M * d;
      const int j0 = i - 1 + base;
      const float* src = Bw + (size_t)j0 * NB;

      if (i == 1) {
        // coarse Euler sweep (i>=2 reuses Eb from previous sequential phase)
        axpy(Cst, Csh, Csl, src, src, 0.f, ne);
        for (int s = 0; s < S; ++s) {
          g1(Csh, Csl, M);
          g2ax(M, Cst, Csh, Csl, Cst, 0.f, 1.f);
        }
      }
      // fine RK4 sweep
      axpy(Xf, Xh, Xl, src, src, 0.f, ne);
      for (int s = 0; s < S; ++s) {
        g1(Xh, Xl, M);   g2rk(M, 1.f / 6.f, 0.5f, 0);   // k1
        g1(XTh, XTl, M); g2rk(M, 1.f / 3.f, 0.5f, 1);   // k2
        g1(XTh, XTl, M); g2rk(M, 1.f / 3.f, 1.0f, 1);   // k3
        g1(XTh, XTl, M); g2ax(M, Xf, Xh, Xl, ACC, 0.f, 1.f / 6.f);  // k4
      }
      const float* Cref = (i == 1) ? Cst : (Eb + (size_t)j0 * NB);
      axpy(Dbuf + (size_t)base * NB, nullptr, nullptr, Xf, Cref, -1.f, ne);
    }

    // ---- sequential Parareal correction: 3 dispatches/substep, 64^2 -------
    const float* start = Bw + (size_t)(i - 1) * NB;
    axpy(Xf, Xh, Xl, start, start, 0.f, NB);
    for (int m = 0; m < rem; ++m) {
      for (int s = 0; s < S; ++s) {
        gemm64_k<1><<<dim3(h / 64, batch / 64, 1), 256, 0, stream>>>(
            Xh, Xl, W1Th, W1Tl, b1, nullptr, Yh, Yl, batch, h, d, d);
        gemm64_k<2><<<dim3(d / 64, batch / 64, SPL2), 256, 0, stream>>>(
            Yh, Yl, W2Th, W2Tl, nullptr, Part, nullptr, nullptr,
            batch, d, h, h / SPL2);
        const bool last = (s == S - 1);
        reduce_axpy_k<<<(MN4d + 255) / 256, 256, 0, stream>>>(
            Part, SPL2, MN4d, tspan, Xf, Xh, Xl,
            last ? Dbuf + (size_t)m * NB : nullptr,
            last ? Bw + (size_t)(i + m) * NB : nullptr,
            last ? Eb + (size_t)(i - 1 + m) * NB : nullptr);
      }
    }
  }
}

// Round 11
// 36199.371 us; speedup vs baseline: 1.0336x; 1.0336x over previous
//
#include <hip/hip_runtime.h>
#include <cstdint>
#include <cstddef>

// ---------------------------------------------------------------------------
// Parareal neural-ODE (MSZero_13761075216509)
// f(x) = tanh(x@W1 + b1) @ W2 ; fp32 via bf16 hi/lo 3-term split MFMA.
// R11: traffic-directed. Vect phase is LLC-BW bound (~2.1GB/f-eval @7.8TB/s,
//      insensitive to schedule R2/R3/R7/R10). Fix: (1) G1 -> 256^2 tile
//      (512thr, 8 waves) halving panel re-reads; (2) bijective XCD-chunked
//      blockIdx swizzle (T1/m204) on all GEMMs so A/Y panels become
//      L2-resident per XCD; (3) G2/seq keep R9-proven kernels + swizzle.
// ---------------------------------------------------------------------------

typedef __attribute__((ext_vector_type(4))) float f32x4;
typedef __attribute__((ext_vector_type(8))) short s16x8;
typedef __attribute__((ext_vector_type(4))) unsigned short u16x4;

#define DEV __device__ __forceinline__

DEV unsigned short f2bf(float x) {
  union { float f; uint32_t u; } v; v.f = x;
  uint32_t r = v.u + 0x7FFFu + ((v.u >> 16) & 1u);   // RNE
  return (unsigned short)(r >> 16);
}
DEV float bf2f(unsigned short h) {
  union { uint32_t u; float f; } v; v.u = ((uint32_t)h) << 16; return v.f;
}
DEV void split2(float x, unsigned short &h, unsigned short &l) {
  h = f2bf(x);
  l = f2bf(x - bf2f(h));
}
DEV float fast_tanh(float z) {
  return 1.f - 2.f / (__expf(2.f * z) + 1.f);
}
DEV void gload16(const unsigned short* g, unsigned short* l) {
  __builtin_amdgcn_global_load_lds(
      (const __attribute__((address_space(1))) void*)g,
      (__attribute__((address_space(3))) void*)l, 16, 0, 0);
}

// bijective XCD-chunked swizzle (m204): hardware lin id -> logical tile id so
// each XCD (lin%8) owns a CONTIGUOUS chunk of logical tiles -> panel reuse
// lands in that XCD's L2. Bijective for any nwg.
DEV void swz3(int &bx, int &by, int &bz) {
  const int gx = gridDim.x, gy = gridDim.y, gz = gridDim.z;
  const int nwg = gx * gy * gz;
  const int lin = (bz * gy + by) * gx + bx;
  const int q = nwg >> 3, r = nwg & 7;
  const int x = lin & 7, j = lin >> 3;
  const int logical = (x < r ? x * (q + 1) : r * (q + 1) + (x - r) * q) + j;
  bx = logical % gx;
  const int t = logical / gx;
  by = t % gy;
  bz = t / gy;
}

// ---------------------------------------------------------------------------
// 128x128 GEMM (R9 dbuf structure + swizzle): C[M,N] = A[M,K]*B[K,N]; A hi/lo
// bf16 [M][K], B pre-transposed hi/lo bf16 [N][K]. Ah*Bh+Ah*Bl+Al*Bh, fp32 acc.
// LDS [128 rows][8 slots x 16B]/operand, phys slot = src ^ (row&7); dbuf,
// prefetch-issue-early.
// EPI=1: v=tanh(acc+bias[col]) -> Oh/Ol bf16
// EPI=3: rk-update: a=(add?ACC:X)+a1*sdt*acc -> ACC ; xt=X+a2*sdt*acc -> Oh/Ol
// EPI=4: axpy-update: v=Xin+(a1+a2*sdt)*acc -> Xout fp32 + Oh/Ol split
// ---------------------------------------------------------------------------
template<int EPI>
__global__ __launch_bounds__(256, 2) void gemm_k(
    const unsigned short* __restrict__ Ah, const unsigned short* __restrict__ Al,
    const unsigned short* __restrict__ Bh, const unsigned short* __restrict__ Bl,
    const float* __restrict__ bias,
    unsigned short* __restrict__ Oh, unsigned short* __restrict__ Ol,
    const float* __restrict__ Xin,
    float* __restrict__ ACCb,
    float* __restrict__ Xout,
    const float* __restrict__ tspan,
    float a1, float a2, int accAdd,
    int M, int N, int K, int KS)
{
  __shared__ unsigned short sA[2][128 * 64];
  __shared__ unsigned short sB[2][128 * 64];
  const int tid = threadIdx.x;
  const int w = tid >> 6, l = tid & 63;
  int bx = blockIdx.x, by = blockIdx.y, bz = blockIdx.z;
  swz3(bx, by, bz);
  const int m0 = by * 128, n0 = bx * 128;
  const int wm = (w >> 1) * 64, wn = (w & 1) * 64;

  f32x4 acc[4][4];
#pragma unroll
  for (int a = 0; a < 4; ++a)
#pragma unroll
    for (int b = 0; b < 4; ++b) acc[a][b] = (f32x4){0.f, 0.f, 0.f, 0.f};

  const int rsub = w * 8 + (l >> 3);
  const int ssrc = (l & 7) ^ (l >> 3);
  const int shalf = ssrc >> 2;
  const int schunk = ssrc & 3;
  const unsigned short* gA = (shalf ? Al : Ah) + (size_t)(m0 + rsub) * K + schunk * 8;
  const unsigned short* gB = (shalf ? Bl : Bh) + (size_t)(n0 + rsub) * K + schunk * 8;
  const size_t gstep = (size_t)32 * (size_t)K;
  const int db = w * 512;

  const int arow = (l & 15);
  const int slotH = ((l >> 4)) ^ (l & 7);
  const int slotL = (4 + (l >> 4)) ^ (l & 7);

  const int nk = KS >> 5;

  auto STAGE = [&](int buf, int kt) {
    const size_t ko = (size_t)kt * 32;
    unsigned short* da = &sA[buf][db];
    unsigned short* dbp = &sB[buf][db];
#pragma unroll
    for (int j = 0; j < 4; ++j) {
      gload16(gA + ko + (size_t)j * gstep, da + j * 2048);
      gload16(gB + ko + (size_t)j * gstep, dbp + j * 2048);
    }
  };

  STAGE(0, 0);
  __syncthreads();
  int cur = 0;

  for (int kt = 0; kt < nk; ++kt) {
    if (kt + 1 < nk) STAGE(cur ^ 1, kt + 1);
    const unsigned short* pa = &sA[cur][0];
    const unsigned short* pb = &sB[cur][0];
    s16x8 afh[4], afl[4], bfh[4], bfl[4];
#pragma unroll
    for (int mi = 0; mi < 4; ++mi) {
      const int rb = (wm + mi * 16 + arow) * 64;
      afh[mi] = *(const s16x8*)&pa[rb + slotH * 8];
      afl[mi] = *(const s16x8*)&pa[rb + slotL * 8];
    }
#pragma unroll
    for (int ni = 0; ni < 4; ++ni) {
      const int rb = (wn + ni * 16 + arow) * 64;
      bfh[ni] = *(const s16x8*)&pb[rb + slotH * 8];
      bfl[ni] = *(const s16x8*)&pb[rb + slotL * 8];
    }
#pragma unroll
    for (int mi = 0; mi < 4; ++mi)
#pragma unroll
      for (int ni = 0; ni < 4; ++ni) {
        acc[mi][ni] = __builtin_amdgcn_mfma_f32_16x16x32_bf16(afh[mi], bfh[ni], acc[mi][ni], 0, 0, 0);
        acc[mi][ni] = __builtin_amdgcn_mfma_f32_16x16x32_bf16(afh[mi], bfl[ni], acc[mi][ni], 0, 0, 0);
        acc[mi][ni] = __builtin_amdgcn_mfma_f32_16x16x32_bf16(afl[mi], bfh[ni], acc[mi][ni], 0, 0, 0);
      }
    __syncthreads();
    cur ^= 1;
  }

  const int colb = n0 + wn + (l & 15);
  const int rowb = m0 + wm + (l >> 4) * 4;
  const float sdt = (EPI >= 3) ? (tspan[1] - tspan[0]) * (1.0f / 7.0f) : 0.f;

  if (EPI == 1) {
#pragma unroll
    for (int mi = 0; mi < 4; ++mi)
#pragma unroll
      for (int ni = 0; ni < 4; ++ni) {
        const int col = colb + ni * 16;
        const float bc = bias[col];
#pragma unroll
        for (int j = 0; j < 4; ++j) {
          const size_t idx = (size_t)(rowb + mi * 16 + j) * N + col;
          const float v = fast_tanh(acc[mi][ni][j] + bc);
          unsigned short hh, ll; split2(v, hh, ll);
          Oh[idx] = hh; Ol[idx] = ll;
        }
      }
  } else if (EPI == 3) {
    const float c1 = a1 * sdt, c2 = a2 * sdt;
#pragma unroll
    for (int mi = 0; mi < 4; ++mi)
#pragma unroll
      for (int ni = 0; ni < 4; ++ni) {
        const int col = colb + ni * 16;
#pragma unroll
        for (int j = 0; j < 4; ++j) {
          const size_t idx = (size_t)(rowb + mi * 16 + j) * N + col;
          const float f = acc[mi][ni][j];
          const float x = Xin[idx];
          const float a = (accAdd ? ACCb[idx] : x) + c1 * f;
          ACCb[idx] = a;
          const float xt = x + c2 * f;
          unsigned short hh, ll; split2(xt, hh, ll);
          Oh[idx] = hh; Ol[idx] = ll;
        }
      }
  } else {  // EPI == 4
    const float coef = a1 + a2 * sdt;
#pragma unroll
    for (int mi = 0; mi < 4; ++mi)
#pragma unroll
      for (int ni = 0; ni < 4; ++ni) {
        const int col = colb + ni * 16;
#pragma unroll
        for (int j = 0; j < 4; ++j) {
          const size_t idx = (size_t)(rowb + mi * 16 + j) * N + col;
          const float v = Xin[idx] + coef * acc[mi][ni][j];
          Xout[idx] = v;
          unsigned short hh, ll; split2(v, hh, ll);
          Oh[idx] = hh; Ol[idx] = ll;
        }
      }
  }
}

// ---------------------------------------------------------------------------
// 256x256 GEMM, 512 threads / 8 waves (2M x 4N), for vect G1 (EPI=1 only).
// Same staging/swizzle algebra as 128^2 (verified formulas; row&7 == l&7 for
// 16-multiple row bases). LDS 64KB single-buffered: [256 rows][8 slots x16B]
// per operand. Halves A- and B-panel re-read factors vs 128^2.
// ---------------------------------------------------------------------------
__global__ __launch_bounds__(512, 1) void gemm256_k(
    const unsigned short* __restrict__ Ah, const unsigned short* __restrict__ Al,
    const unsigned short* __restrict__ Bh, const unsigned short* __restrict__ Bl,
    const float* __restrict__ bias,
    unsigned short* __restrict__ Oh, unsigned short* __restrict__ Ol,
    int M, int N, int K)
{
  __shared__ unsigned short sA[256 * 64];   // 32 KB
  __shared__ unsigned short sB[256 * 64];   // 32 KB
  const int tid = threadIdx.x;
  const int w = tid >> 6, l = tid & 63;     // w = 0..7
  int bx = blockIdx.x, by = blockIdx.y, bz = blockIdx.z;
  swz3(bx, by, bz);
  const int m0 = by * 256, n0 = bx * 256;
  const int wm = (w >> 2) * 128;            // 2 waves in M
  const int wn = (w & 3) * 64;              // 4 waves in N

  f32x4 acc[8][4];
#pragma unroll
  for (int a = 0; a < 8; ++a)
#pragma unroll
    for (int b = 0; b < 4; ++b) acc[a][b] = (f32x4){0.f, 0.f, 0.f, 0.f};

  // staging: call j writes bytes [w*1024 + j*8192 + lane*16)
  //   -> row j*64 + w*8 + (l>>3), phys slot l&7 holding src ^ (row&7)
  const int rsub = w * 8 + (l >> 3);
  const int ssrc = (l & 7) ^ (l >> 3);
  const int shalf = ssrc >> 2;
  const int schunk = ssrc & 3;
  const unsigned short* gA = (shalf ? Al : Ah) + (size_t)(m0 + rsub) * K + schunk * 8;
  const unsigned short* gB = (shalf ? Bl : Bh) + (size_t)(n0 + rsub) * K + schunk * 8;
  const size_t gstep = (size_t)64 * (size_t)K;   // +64 rows per call j
  const int db = w * 512;                        // ushort idx (w*1024 bytes)

  const int arow = (l & 15);
  const int slotH = ((l >> 4)) ^ (l & 7);
  const int slotL = (4 + (l >> 4)) ^ (l & 7);

  const int nk = K >> 5;

  for (int kt = 0; kt < nk; ++kt) {
    const size_t ko = (size_t)kt * 32;
#pragma unroll
    for (int j = 0; j < 4; ++j) {
      gload16(gA + ko + (size_t)j * gstep, &sA[db + j * 4096]);
      gload16(gB + ko + (size_t)j * gstep, &sB[db + j * 4096]);
    }
    __syncthreads();

    s16x8 bfh[4], bfl[4];
#pragma unroll
    for (int ni = 0; ni < 4; ++ni) {
      const int rb = (wn + ni * 16 + arow) * 64;
      bfh[ni] = *(const s16x8*)&sB[rb + slotH * 8];
      bfl[ni] = *(const s16x8*)&sB[rb + slotL * 8];
    }
#pragma unroll
    for (int mi = 0; mi < 8; ++mi) {
      const int rb = (wm + mi * 16 + arow) * 64;
      const s16x8 afh = *(const s16x8*)&sA[rb + slotH * 8];
      const s16x8 afl = *(const s16x8*)&sA[rb + slotL * 8];
#pragma unroll
      for (int ni = 0; ni < 4; ++ni) {
        acc[mi][ni] = __builtin_amdgcn_mfma_f32_16x16x32_bf16(afh, bfh[ni], acc[mi][ni], 0, 0, 0);
        acc[mi][ni] = __builtin_amdgcn_mfma_f32_16x16x32_bf16(afh, bfl[ni], acc[mi][ni], 0, 0, 0);
        acc[mi][ni] = __builtin_amdgcn_mfma_f32_16x16x32_bf16(afl, bfh[ni], acc[mi][ni], 0, 0, 0);
      }
    }
    __syncthreads();
  }

  // epilogue: row = m0+wm+mi*16+(l>>4)*4+j, col = n0+wn+ni*16+(l&15)
  const int colb = n0 + wn + (l & 15);
  const int rowb = m0 + wm + (l >> 4) * 4;
#pragma unroll
  for (int mi = 0; mi < 8; ++mi)
#pragma unroll
    for (int ni = 0; ni < 4; ++ni) {
      const int col = colb + ni * 16;
      const float bc = bias[col];
#pragma unroll
      for (int j = 0; j < 4; ++j) {
        const size_t idx = (size_t)(rowb + mi * 16 + j) * N + col;
        const float v = fast_tanh(acc[mi][ni][j] + bc);
        unsigned short hh, ll; split2(v, hh, ll);
        Oh[idx] = hh; Ol[idx] = ll;
      }
    }
}

// ---------------------------------------------------------------------------
// 64x64 GEMM for the sequential phase (R9 + swizzle)
// EPI=1: tanh(acc+bias)->Oh/Ol.  EPI=2: Part + bz*M*N partial.
// ---------------------------------------------------------------------------
template<int EPI>
__global__ __launch_bounds__(256, 2) void gemm64_k(
    const unsigned short* __restrict__ Ah, const unsigned short* __restrict__ Al,
    const unsigned short* __restrict__ Bh, const unsigned short* __restrict__ Bl,
    const float* __restrict__ bias,
    float* __restrict__ Part,
    unsigned short* __restrict__ Oh, unsigned short* __restrict__ Ol,
    int M, int N, int K, int KS)
{
  __shared__ unsigned short sA[2][64 * 64];
  __shared__ unsigned short sB[2][64 * 64];
  const int tid = threadIdx.x;
  const int w = tid >> 6, l = tid & 63;
  int bx = blockIdx.x, by = blockIdx.y, bz = blockIdx.z;
  swz3(bx, by, bz);
  const int m0 = by * 64, n0 = bx * 64;
  const size_t kbeg = (size_t)bz * (size_t)KS;
  const int wm = (w >> 1) * 32, wn = (w & 1) * 32;

  f32x4 acc[2][2];
#pragma unroll
  for (int a = 0; a < 2; ++a)
#pragma unroll
    for (int b = 0; b < 2; ++b) acc[a][b] = (f32x4){0.f, 0.f, 0.f, 0.f};

  const int rsub = w * 8 + (l >> 3);
  const int ssrc = (l & 7) ^ (l >> 3);
  const int shalf = ssrc >> 2;
  const int schunk = ssrc & 3;
  const unsigned short* gA = (shalf ? Al : Ah) + (size_t)(m0 + rsub) * K + kbeg + schunk * 8;
  const unsigned short* gB = (shalf ? Bl : Bh) + (size_t)(n0 + rsub) * K + kbeg + schunk * 8;
  const size_t gstep = (size_t)32 * (size_t)K;
  const int db = w * 512;

  const int arow = (l & 15);
  const int slotH = ((l >> 4)) ^ (l & 7);
  const int slotL = (4 + (l >> 4)) ^ (l & 7);

  const int nk = KS >> 5;

  auto STAGE = [&](int buf, int kt) {
    const size_t ko = (size_t)kt * 32;
    unsigned short* da = &sA[buf][db];
    unsigned short* dbp = &sB[buf][db];
#pragma unroll
    for (int j = 0; j < 2; ++j) {
      gload16(gA + ko + (size_t)j * gstep, da + j * 2048);
      gload16(gB + ko + (size_t)j * gstep, dbp + j * 2048);
    }
  };

  STAGE(0, 0);
  __syncthreads();
  int cur = 0;

  for (int kt = 0; kt < nk; ++kt) {
    if (kt + 1 < nk) STAGE(cur ^ 1, kt + 1);
    const unsigned short* pa = &sA[cur][0];
    const unsigned short* pb = &sB[cur][0];
    s16x8 afh[2], afl[2], bfh[2], bfl[2];
#pragma unroll
    for (int mi = 0; mi < 2; ++mi) {
      const int rb = (wm + mi * 16 + arow) * 64;
      afh[mi] = *(const s16x8*)&pa[rb + slotH * 8];
      afl[mi] = *(const s16x8*)&pa[rb + slotL * 8];
    }
#pragma unroll
    for (int ni = 0; ni < 2; ++ni) {
      const int rb = (wn + ni * 16 + arow) * 64;
      bfh[ni] = *(const s16x8*)&pb[rb + slotH * 8];
      bfl[ni] = *(const s16x8*)&pb[rb + slotL * 8];
    }
#pragma unroll
    for (int mi = 0; mi < 2; ++mi)
#pragma unroll
      for (int ni = 0; ni < 2; ++ni) {
        acc[mi][ni] = __builtin_amdgcn_mfma_f32_16x16x32_bf16(afh[mi], bfh[ni], acc[mi][ni], 0, 0, 0);
        acc[mi][ni] = __builtin_amdgcn_mfma_f32_16x16x32_bf16(afh[mi], bfl[ni], acc[mi][ni], 0, 0, 0);
        acc[mi][ni] = __builtin_amdgcn_mfma_f32_16x16x32_bf16(afl[mi], bfh[ni], acc[mi][ni], 0, 0, 0);
      }
    __syncthreads();
    cur ^= 1;
  }

  const int colb = n0 + wn + (l & 15);
  const int rowb = m0 + wm + (l >> 4) * 4;

  if (EPI == 1) {
#pragma unroll
    for (int mi = 0; mi < 2; ++mi)
#pragma unroll
      for (int ni = 0; ni < 2; ++ni) {
        const int col = colb + ni * 16;
        const float bc = bias[col];
#pragma unroll
        for (int j = 0; j < 4; ++j) {
          const size_t idx = (size_t)(rowb + mi * 16 + j) * N + col;
          const float v = fast_tanh(acc[mi][ni][j] + bc);
          unsigned short hh, ll; split2(v, hh, ll);
          Oh[idx] = hh; Ol[idx] = ll;
        }
      }
  } else {
    float* dst = Part + (size_t)bz * (size_t)M * N;
#pragma unroll
    for (int mi = 0; mi < 2; ++mi)
#pragma unroll
      for (int ni = 0; ni < 2; ++ni) {
        const int col = colb + ni * 16;
#pragma unroll
        for (int j = 0; j < 4; ++j)
          dst[(size_t)(rowb + mi * 16 + j) * N + col] = acc[mi][ni][j];
      }
  }
}

// ---------------------------------------------------------------------------
// seq GEMM2 finish: F = sum_z Part[z]; E = X + sdt*F; [Eout=E];
// v = E [+ Dv]; X = v (+ hi/lo split); [Bout=v]
// ---------------------------------------------------------------------------
__global__ void reduce_axpy_k(const float* __restrict__ part, int S, int MN4,
    const float* __restrict__ tspan,
    float* __restrict__ Xf, unsigned short* __restrict__ Xh, unsigned short* __restrict__ Xl,
    const float* __restrict__ Dv, float* __restrict__ Bout, float* __restrict__ Eout)
{
  const int i = blockIdx.x * blockDim.x + threadIdx.x;
  if (i >= MN4) return;
  const float sdt = (tspan[1] - tspan[0]) * (1.0f / 7.0f);
  const size_t MN = (size_t)MN4 * 4;
  const size_t o = 4 * (size_t)i;
  f32x4 s = *(const f32x4*)(part + o);
  for (int z = 1; z < S; ++z) s += *(const f32x4*)(part + (size_t)z * MN + o);
  f32x4 e = *(const f32x4*)(Xf + o) + sdt * s;
  if (Eout) *(f32x4*)(Eout + o) = e;
  f32x4 v = e;
  if (Dv) v += *(const f32x4*)(Dv + o);
  *(f32x4*)(Xf + o) = v;
  u16x4 hh, ll;
#pragma unroll
  for (int j = 0; j < 4; ++j) { unsigned short h_, l_; split2(v[j], h_, l_); hh[j] = h_; ll[j] = l_; }
  *(u16x4*)(Xh + o) = hh;
  *(u16x4*)(Xl + o) = ll;
  if (Bout) *(f32x4*)(Bout + o) = v;
}

// ---------------------------------------------------------------------------
__global__ void axpy_split_k(
    float* __restrict__ dstF, unsigned short* __restrict__ dstH,
    unsigned short* __restrict__ dstL,
    const float* __restrict__ A, const float* __restrict__ Fv,
    float coef, int n4)
{
  for (int i = blockIdx.x * blockDim.x + threadIdx.x; i < n4;
       i += gridDim.x * blockDim.x) {
    const size_t o = 4 * (size_t)i;
    const f32x4 a = *(const f32x4*)(A + o);
    const f32x4 f = *(const f32x4*)(Fv + o);
    f32x4 v = a + coef * f;
    *(f32x4*)(dstF + o) = v;
    if (dstH) {
      u16x4 hh, ll;
#pragma unroll
      for (int j = 0; j < 4; ++j) { unsigned short h_, l_; split2(v[j], h_, l_); hh[j] = h_; ll[j] = l_; }
      *(u16x4*)(dstH + o) = hh;
      *(u16x4*)(dstL + o) = ll;
    }
  }
}

// ---------------------------------------------------------------------------
__global__ void transpose_split_k(const float* __restrict__ W,
                                  unsigned short* __restrict__ Th,
                                  unsigned short* __restrict__ Tl,
                                  int K, int N)
{
  __shared__ float t[32][33];
  const int tx = threadIdx.x & 31, ty = threadIdx.x >> 5;
  const int n0 = blockIdx.x * 32, k0 = blockIdx.y * 32;
#pragma unroll
  for (int r = 0; r < 4; ++r) {
    const int row = ty + r * 8;
    t[row][tx] = W[(size_t)(k0 + row) * N + n0 + tx];
  }
  __syncthreads();
#pragma unroll
  for (int r = 0; r < 4; ++r) {
    const int row = ty + r * 8;
    const float v = t[tx][row];
    unsigned short hh, ll; split2(v, hh, ll);
    const size_t idx = (size_t)(n0 + row) * K + k0 + tx;
    Th[idx] = hh; Tl[idx] = ll;
  }
}

// ---------------------------------------------------------------------------
extern "C" void kernel_launch(void* const* d_in, const int* in_sizes, int n_in,
                              void* d_out, int out_size, void* d_ws, size_t ws_size,
                              hipStream_t stream)
{
  const float* Bin   = (const float*)d_in[0];
  const float* tspan = (const float*)d_in[1];
  const float* W1    = (const float*)d_in[2];
  const float* b1    = (const float*)d_in[3];
  const float* W2    = (const float*)d_in[4];

  const int n = in_sizes[1];                 // 16
  const int h = in_sizes[3];                 // 4096
  const int d = in_sizes[2] / h;             // 1024
  const int batch = in_sizes[0] / (n * d);   // 256
  const int S = 7;                           // fine_steps-1
  const int MAXIT = 2;
  const size_t NB = (size_t)batch * d;

  float* Bw = (float*)d_out;

  uint8_t* wsb = (uint8_t*)d_ws;
  size_t off = 0;
  auto carve = [&](size_t bytes) -> void* {
    off = (off + 255) & ~(size_t)255;
    void* p = wsb + off; off += bytes; return p;
  };

  const size_t WH = (size_t)d * h;
  unsigned short* W1Th = (unsigned short*)carve(WH * 2);
  unsigned short* W1Tl = (unsigned short*)carve(WH * 2);
  unsigned short* W2Th = (unsigned short*)carve(WH * 2);
  unsigned short* W2Tl = (unsigned short*)carve(WH * 2);
  float* Dbuf = (float*)carve((size_t)(n - 1) * NB * 4);
  float* Eb   = (float*)carve((size_t)n * NB * 4);

  // seq GEMM2 partials: z=4 x batch x d (4.2 MB)
  const int SPL2 = 4;
  float* Part = (float*)carve((size_t)SPL2 * NB * 4);

  // per node: Cst4 + Csh2 + Csl2 + Xf4 + Xh2 + Xl2 + ACC4 (XT aliases Cs) + Y4
  const size_t per_node = NB * 20 + (size_t)batch * h * 4;
  int c;
  {
    size_t remb = ws_size > off + (1u << 20) ? ws_size - off - (1u << 20) : 0;
    c = (int)(remb / per_node);
    if (c < 1) c = 1;
    if (c > n - 1) c = n - 1;
  }
  const size_t CE = (size_t)c * NB;
  float*          Cst = (float*)carve(CE * 4);
  unsigned short* Csh = (unsigned short*)carve(CE * 2);
  unsigned short* Csl = (unsigned short*)carve(CE * 2);
  float*          Xf  = (float*)carve(CE * 4);
  unsigned short* Xh  = (unsigned short*)carve(CE * 2);
  unsigned short* Xl  = (unsigned short*)carve(CE * 2);
  float*          ACC = (float*)carve(CE * 4);
  unsigned short* Yh  = (unsigned short*)carve((size_t)c * batch * h * 2);
  unsigned short* Yl  = (unsigned short*)carve((size_t)c * batch * h * 2);
  unsigned short* XTh = Csh;   // time-disjoint with coarse sweep
  unsigned short* XTl = Csl;

  auto ewg = [](size_t n4) -> int {
    size_t g = (n4 + 255) / 256;
    if (g > 2048) g = 2048; if (g < 1) g = 1;
    return (int)g;
  };
  auto axpy = [&](float* dF, unsigned short* dH, unsigned short* dL,
                  const float* A, const float* Fv, float coef, size_t ne) {
    const int n4 = (int)(ne / 4);
    axpy_split_k<<<ewg(n4), 256, 0, stream>>>(dF, dH, dL, A, Fv, coef, n4);
  };
  // vect g1: 256^2 tile when M allows (M multiple of 256 always; need >=1024
  // for useful width), else 128^2 fallback. Fused tanh+split epilogue.
  auto g1 = [&](const unsigned short* xh, const unsigned short* xl, int M) {
    if (M >= 1024) {
      gemm256_k<<<dim3(h / 256, M / 256, 1), 512, 0, stream>>>(
          xh, xl, W1Th, W1Tl, b1, Yh, Yl, M, h, d);
    } else {
      gemm_k<1><<<dim3(h / 128, M / 128, 1), 256, 0, stream>>>(
          xh, xl, W1Th, W1Tl, b1, Yh, Yl,
          nullptr, nullptr, nullptr, tspan, 0.f, 0.f, 0, M, h, d, d);
    }
  };
  auto g2rk = [&](int M, float a1, float a2, int add) {
    gemm_k<3><<<dim3(d / 128, M / 128, 1), 256, 0, stream>>>(
        Yh, Yl, W2Th, W2Tl, nullptr, XTh, XTl,
        Xf, ACC, nullptr, tspan, a1, a2, add, M, d, h, h);
  };
  auto g2ax = [&](int M, float* dF, unsigned short* dH, unsigned short* dL,
                  const float* Xin, float a1, float a2) {
    gemm_k<4><<<dim3(d / 128, M / 128, 1), 256, 0, stream>>>(
        Yh, Yl, W2Th, W2Tl, nullptr, dH, dL,
        Xin, nullptr, dF, tspan, a1, a2, 0, M, d, h, h);
  };

  // ---- prep ---------------------------------------------------------------
  hipMemcpyAsync(Bw, Bin, (size_t)n * NB * 4, hipMemcpyDeviceToDevice, stream);
  transpose_split_k<<<dim3(h / 32, d / 32), 256, 0, stream>>>(W1, W1Th, W1Tl, d, h);
  transpose_split_k<<<dim3(d / 32, h / 32), 256, 0, stream>>>(W2, W2Th, W2Tl, h, d);

  const int MN4d = (int)(NB / 4);

  // ---- Parareal outer loop ------------------------------------------------
  for (int i = 1; i <= MAXIT + 1; ++i) {
    const int rem = n - i;

    for (int base = 0; base < rem; base += c) {
      const int cc = (rem - base) < c ? (rem - base) : c;
      const int M = cc * batch;
      const size_t ne = (size_t)M * d;
      const int j0 = i - 1 + base;
      const float* src = Bw + (size_t)j0 * NB;

      if (i == 1) {
        // coarse Euler sweep (i>=2 reuses Eb from previous sequential phase)
        axpy(Cst, Csh, Csl, src, src, 0.f, ne);
        for (int s = 0; s < S; ++s) {
          g1(Csh, Csl, M);
          g2ax(M, Cst, Csh, Csl, Cst, 0.f, 1.f);
        }
      }
      // fine RK4 sweep
      axpy(Xf, Xh, Xl, src, src, 0.f, ne);
      for (int s = 0; s < S; ++s) {
        g1(Xh, Xl, M);   g2rk(M, 1.f / 6.f, 0.5f, 0);   // k1
        g1(XTh, XTl, M); g2rk(M, 1.f / 3.f, 0.5f, 1);   // k2
        g1(XTh, XTl, M); g2rk(M, 1.f / 3.f, 1.0f, 1);   // k3
        g1(XTh, XTl, M); g2ax(M, Xf, Xh, Xl, ACC, 0.f, 1.f / 6.f);  // k4
      }
      const float* Cref = (i == 1) ? Cst : (Eb + (size_t)j0 * NB);
      axpy(Dbuf + (size_t)base * NB, nullptr, nullptr, Xf, Cref, -1.f, ne);
    }

    // ---- sequential Parareal correction: 3 dispatches/substep, 64^2 -------
    const float* start = Bw + (size_t)(i - 1) * NB;
    axpy(Xf, Xh, Xl, start, start, 0.f, NB);
    for (int m = 0; m < rem; ++m) {
      for (int s = 0; s < S; ++s) {
        gemm64_k<1><<<dim3(h / 64, batch / 64, 1), 256, 0, stream>>>(
            Xh, Xl, W1Th, W1Tl, b1, nullptr, Yh, Yl, batch, h, d, d);
        gemm64_k<2><<<dim3(d / 64, batch / 64, SPL2), 256, 0, stream>>>(
            Yh, Yl, W2Th, W2Tl, nullptr, Part, nullptr, nullptr,
            batch, d, h, h / SPL2);
        const bool last = (s == S - 1);
        reduce_axpy_k<<<(MN4d + 255) / 256, 256, 0, stream>>>(
            Part, SPL2, MN4d, tspan, Xf, Xh, Xl,
            last ? Dbuf + (size_t)m * NB : nullptr,
            last ? Bw + (size_t)(i + m) * NB : nullptr,
            last ? Eb + (size_t)(i - 1 + m) * NB : nullptr);
      }
    }
  }
}

// Round 12
// 36128.000 us; speedup vs baseline: 1.0356x; 1.0020x over previous
//
#include <hip/hip_runtime.h>
#include <cstdint>
#include <cstddef>

// ---------------------------------------------------------------------------
// Parareal neural-ODE (MSZero_13761075216509)
// f(x) = tanh(x@W1 + b1) @ W2 ; fp32 via bf16 hi/lo 3-term split MFMA.
// R12: 2-D SUPERTILE XCD swizzle on every GEMM (each XCD gets STXxSTY tile
//      supertiles, column-major supertile order) so the per-XCD working set
//      (A-tiles + W-strips) fits the 4MB L2 -> panel re-reads become L2 hits
//      instead of LLC traffic (vect AND seq are LLC-BW-bound, R7 marginal
//      measurement ~8.4TB/s). 256^2 G1 gate raised to M>=3072 (underfill
//      crossover). Everything else identical to R11 (36.2ms).
// ---------------------------------------------------------------------------

typedef __attribute__((ext_vector_type(4))) float f32x4;
typedef __attribute__((ext_vector_type(8))) short s16x8;
typedef __attribute__((ext_vector_type(4))) unsigned short u16x4;

#define DEV __device__ __forceinline__

DEV unsigned short f2bf(float x) {
  union { float f; uint32_t u; } v; v.f = x;
  uint32_t r = v.u + 0x7FFFu + ((v.u >> 16) & 1u);   // RNE
  return (unsigned short)(r >> 16);
}
DEV float bf2f(unsigned short h) {
  union { uint32_t u; float f; } v; v.u = ((uint32_t)h) << 16; return v.f;
}
DEV void split2(float x, unsigned short &h, unsigned short &l) {
  h = f2bf(x);
  l = f2bf(x - bf2f(h));
}
DEV float fast_tanh(float z) {
  return 1.f - 2.f / (__expf(2.f * z) + 1.f);
}
DEV void gload16(const unsigned short* g, unsigned short* l) {
  __builtin_amdgcn_global_load_lds(
      (const __attribute__((address_space(1))) void*)g,
      (__attribute__((address_space(3))) void*)l, 16, 0, 0);
}

// ---------------------------------------------------------------------------
// 2-D supertile XCD swizzle. Bijective m204 chunking (XCD = lin%8 owns a
// contiguous logical range), then logical -> (bx,by,bz) through STXxSTY
// supertiles ordered column-major (consecutive supertiles share W-strips).
// Requires STX|gridDim.x, STY|gridDim.y (host guarantees via pickst).
// Pure block permutation: results bit-identical.
// ---------------------------------------------------------------------------
DEV void swz_st(int &bx, int &by, int &bz, int STX, int STY) {
  const int gx = gridDim.x, gy = gridDim.y, gz = gridDim.z;
  const int nwg = gx * gy * gz;
  const int lin = (blockIdx.z * gy + blockIdx.y) * gx + blockIdx.x;
  const int q = nwg >> 3, r = nwg & 7;
  const int x = lin & 7, j = lin >> 3;
  const int logical = (x < r ? x * (q + 1) : r * (q + 1) + (x - r) * q) + j;
  const int plane = gx * gy;
  bz = logical / plane;
  const int p = logical % plane;
  const int bps = STX * STY;
  const int sgy = gy / STY;
  const int stid = p / bps;
  const int wid = p % bps;
  const int stx = stid / sgy;     // column-major supertile order
  const int sty = stid % sgy;
  bx = stx * STX + wid % STX;
  by = sty * STY + wid / STX;
}

// ---------------------------------------------------------------------------
// 128x128 GEMM (R9 dbuf structure + supertile swizzle).
// EPI=1: v=tanh(acc+bias[col]) -> Oh/Ol bf16
// EPI=3: rk-update: a=(add?ACC:X)+a1*sdt*acc -> ACC ; xt=X+a2*sdt*acc -> Oh/Ol
// EPI=4: axpy-update: v=Xin+(a1+a2*sdt)*acc -> Xout fp32 + Oh/Ol split
// ---------------------------------------------------------------------------
template<int EPI>
__global__ __launch_bounds__(256, 2) void gemm_k(
    const unsigned short* __restrict__ Ah, const unsigned short* __restrict__ Al,
    const unsigned short* __restrict__ Bh, const unsigned short* __restrict__ Bl,
    const float* __restrict__ bias,
    unsigned short* __restrict__ Oh, unsigned short* __restrict__ Ol,
    const float* __restrict__ Xin,
    float* __restrict__ ACCb,
    float* __restrict__ Xout,
    const float* __restrict__ tspan,
    float a1, float a2, int accAdd,
    int M, int N, int K, int KS, int STX, int STY)
{
  __shared__ unsigned short sA[2][128 * 64];
  __shared__ unsigned short sB[2][128 * 64];
  const int tid = threadIdx.x;
  const int w = tid >> 6, l = tid & 63;
  int bx, by, bz;
  swz_st(bx, by, bz, STX, STY);
  const int m0 = by * 128, n0 = bx * 128;
  const int wm = (w >> 1) * 64, wn = (w & 1) * 64;

  f32x4 acc[4][4];
#pragma unroll
  for (int a = 0; a < 4; ++a)
#pragma unroll
    for (int b = 0; b < 4; ++b) acc[a][b] = (f32x4){0.f, 0.f, 0.f, 0.f};

  const int rsub = w * 8 + (l >> 3);
  const int ssrc = (l & 7) ^ (l >> 3);
  const int shalf = ssrc >> 2;
  const int schunk = ssrc & 3;
  const unsigned short* gA = (shalf ? Al : Ah) + (size_t)(m0 + rsub) * K + schunk * 8;
  const unsigned short* gB = (shalf ? Bl : Bh) + (size_t)(n0 + rsub) * K + schunk * 8;
  const size_t gstep = (size_t)32 * (size_t)K;
  const int db = w * 512;

  const int arow = (l & 15);
  const int slotH = ((l >> 4)) ^ (l & 7);
  const int slotL = (4 + (l >> 4)) ^ (l & 7);

  const int nk = KS >> 5;

  auto STAGE = [&](int buf, int kt) {
    const size_t ko = (size_t)kt * 32;
    unsigned short* da = &sA[buf][db];
    unsigned short* dbp = &sB[buf][db];
#pragma unroll
    for (int j = 0; j < 4; ++j) {
      gload16(gA + ko + (size_t)j * gstep, da + j * 2048);
      gload16(gB + ko + (size_t)j * gstep, dbp + j * 2048);
    }
  };

  STAGE(0, 0);
  __syncthreads();
  int cur = 0;

  for (int kt = 0; kt < nk; ++kt) {
    if (kt + 1 < nk) STAGE(cur ^ 1, kt + 1);
    const unsigned short* pa = &sA[cur][0];
    const unsigned short* pb = &sB[cur][0];
    s16x8 afh[4], afl[4], bfh[4], bfl[4];
#pragma unroll
    for (int mi = 0; mi < 4; ++mi) {
      const int rb = (wm + mi * 16 + arow) * 64;
      afh[mi] = *(const s16x8*)&pa[rb + slotH * 8];
      afl[mi] = *(const s16x8*)&pa[rb + slotL * 8];
    }
#pragma unroll
    for (int ni = 0; ni < 4; ++ni) {
      const int rb = (wn + ni * 16 + arow) * 64;
      bfh[ni] = *(const s16x8*)&pb[rb + slotH * 8];
      bfl[ni] = *(const s16x8*)&pb[rb + slotL * 8];
    }
#pragma unroll
    for (int mi = 0; mi < 4; ++mi)
#pragma unroll
      for (int ni = 0; ni < 4; ++ni) {
        acc[mi][ni] = __builtin_amdgcn_mfma_f32_16x16x32_bf16(afh[mi], bfh[ni], acc[mi][ni], 0, 0, 0);
        acc[mi][ni] = __builtin_amdgcn_mfma_f32_16x16x32_bf16(afh[mi], bfl[ni], acc[mi][ni], 0, 0, 0);
        acc[mi][ni] = __builtin_amdgcn_mfma_f32_16x16x32_bf16(afl[mi], bfh[ni], acc[mi][ni], 0, 0, 0);
      }
    __syncthreads();
    cur ^= 1;
  }

  const int colb = n0 + wn + (l & 15);
  const int rowb = m0 + wm + (l >> 4) * 4;
  const float sdt = (EPI >= 3) ? (tspan[1] - tspan[0]) * (1.0f / 7.0f) : 0.f;

  if (EPI == 1) {
#pragma unroll
    for (int mi = 0; mi < 4; ++mi)
#pragma unroll
      for (int ni = 0; ni < 4; ++ni) {
        const int col = colb + ni * 16;
        const float bc = bias[col];
#pragma unroll
        for (int j = 0; j < 4; ++j) {
          const size_t idx = (size_t)(rowb + mi * 16 + j) * N + col;
          const float v = fast_tanh(acc[mi][ni][j] + bc);
          unsigned short hh, ll; split2(v, hh, ll);
          Oh[idx] = hh; Ol[idx] = ll;
        }
      }
  } else if (EPI == 3) {
    const float c1 = a1 * sdt, c2 = a2 * sdt;
#pragma unroll
    for (int mi = 0; mi < 4; ++mi)
#pragma unroll
      for (int ni = 0; ni < 4; ++ni) {
        const int col = colb + ni * 16;
#pragma unroll
        for (int j = 0; j < 4; ++j) {
          const size_t idx = (size_t)(rowb + mi * 16 + j) * N + col;
          const float f = acc[mi][ni][j];
          const float x = Xin[idx];
          const float a = (accAdd ? ACCb[idx] : x) + c1 * f;
          ACCb[idx] = a;
          const float xt = x + c2 * f;
          unsigned short hh, ll; split2(xt, hh, ll);
          Oh[idx] = hh; Ol[idx] = ll;
        }
      }
  } else {  // EPI == 4
    const float coef = a1 + a2 * sdt;
#pragma unroll
    for (int mi = 0; mi < 4; ++mi)
#pragma unroll
      for (int ni = 0; ni < 4; ++ni) {
        const int col = colb + ni * 16;
#pragma unroll
        for (int j = 0; j < 4; ++j) {
          const size_t idx = (size_t)(rowb + mi * 16 + j) * N + col;
          const float v = Xin[idx] + coef * acc[mi][ni][j];
          Xout[idx] = v;
          unsigned short hh, ll; split2(v, hh, ll);
          Oh[idx] = hh; Ol[idx] = ll;
        }
      }
  }
}

// ---------------------------------------------------------------------------
// 256x256 GEMM, 512 threads / 8 waves (2M x 4N), vect G1 when M>=3072.
// ---------------------------------------------------------------------------
__global__ __launch_bounds__(512, 1) void gemm256_k(
    const unsigned short* __restrict__ Ah, const unsigned short* __restrict__ Al,
    const unsigned short* __restrict__ Bh, const unsigned short* __restrict__ Bl,
    const float* __restrict__ bias,
    unsigned short* __restrict__ Oh, unsigned short* __restrict__ Ol,
    int M, int N, int K, int STX, int STY)
{
  __shared__ unsigned short sA[256 * 64];   // 32 KB
  __shared__ unsigned short sB[256 * 64];   // 32 KB
  const int tid = threadIdx.x;
  const int w = tid >> 6, l = tid & 63;
  int bx, by, bz;
  swz_st(bx, by, bz, STX, STY);
  const int m0 = by * 256, n0 = bx * 256;
  const int wm = (w >> 2) * 128;
  const int wn = (w & 3) * 64;

  f32x4 acc[8][4];
#pragma unroll
  for (int a = 0; a < 8; ++a)
#pragma unroll
    for (int b = 0; b < 4; ++b) acc[a][b] = (f32x4){0.f, 0.f, 0.f, 0.f};

  const int rsub = w * 8 + (l >> 3);
  const int ssrc = (l & 7) ^ (l >> 3);
  const int shalf = ssrc >> 2;
  const int schunk = ssrc & 3;
  const unsigned short* gA = (shalf ? Al : Ah) + (size_t)(m0 + rsub) * K + schunk * 8;
  const unsigned short* gB = (shalf ? Bl : Bh) + (size_t)(n0 + rsub) * K + schunk * 8;
  const size_t gstep = (size_t)64 * (size_t)K;
  const int db = w * 512;

  const int arow = (l & 15);
  const int slotH = ((l >> 4)) ^ (l & 7);
  const int slotL = (4 + (l >> 4)) ^ (l & 7);

  const int nk = K >> 5;

  for (int kt = 0; kt < nk; ++kt) {
    const size_t ko = (size_t)kt * 32;
#pragma unroll
    for (int j = 0; j < 4; ++j) {
      gload16(gA + ko + (size_t)j * gstep, &sA[db + j * 4096]);
      gload16(gB + ko + (size_t)j * gstep, &sB[db + j * 4096]);
    }
    __syncthreads();

    s16x8 bfh[4], bfl[4];
#pragma unroll
    for (int ni = 0; ni < 4; ++ni) {
      const int rb = (wn + ni * 16 + arow) * 64;
      bfh[ni] = *(const s16x8*)&sB[rb + slotH * 8];
      bfl[ni] = *(const s16x8*)&sB[rb + slotL * 8];
    }
#pragma unroll
    for (int mi = 0; mi < 8; ++mi) {
      const int rb = (wm + mi * 16 + arow) * 64;
      const s16x8 afh = *(const s16x8*)&sA[rb + slotH * 8];
      const s16x8 afl = *(const s16x8*)&sA[rb + slotL * 8];
#pragma unroll
      for (int ni = 0; ni < 4; ++ni) {
        acc[mi][ni] = __builtin_amdgcn_mfma_f32_16x16x32_bf16(afh, bfh[ni], acc[mi][ni], 0, 0, 0);
        acc[mi][ni] = __builtin_amdgcn_mfma_f32_16x16x32_bf16(afh, bfl[ni], acc[mi][ni], 0, 0, 0);
        acc[mi][ni] = __builtin_amdgcn_mfma_f32_16x16x32_bf16(afl, bfh[ni], acc[mi][ni], 0, 0, 0);
      }
    }
    __syncthreads();
  }

  const int colb = n0 + wn + (l & 15);
  const int rowb = m0 + wm + (l >> 4) * 4;
#pragma unroll
  for (int mi = 0; mi < 8; ++mi)
#pragma unroll
    for (int ni = 0; ni < 4; ++ni) {
      const int col = colb + ni * 16;
      const float bc = bias[col];
#pragma unroll
      for (int j = 0; j < 4; ++j) {
        const size_t idx = (size_t)(rowb + mi * 16 + j) * N + col;
        const float v = fast_tanh(acc[mi][ni][j] + bc);
        unsigned short hh, ll; split2(v, hh, ll);
        Oh[idx] = hh; Ol[idx] = ll;
      }
    }
}

// ---------------------------------------------------------------------------
// 64x64 GEMM for the sequential phase (R9 + supertile swizzle)
// EPI=1: tanh(acc+bias)->Oh/Ol.  EPI=2: Part + bz*M*N partial.
// ---------------------------------------------------------------------------
template<int EPI>
__global__ __launch_bounds__(256, 2) void gemm64_k(
    const unsigned short* __restrict__ Ah, const unsigned short* __restrict__ Al,
    const unsigned short* __restrict__ Bh, const unsigned short* __restrict__ Bl,
    const float* __restrict__ bias,
    float* __restrict__ Part,
    unsigned short* __restrict__ Oh, unsigned short* __restrict__ Ol,
    int M, int N, int K, int KS, int STX, int STY)
{
  __shared__ unsigned short sA[2][64 * 64];
  __shared__ unsigned short sB[2][64 * 64];
  const int tid = threadIdx.x;
  const int w = tid >> 6, l = tid & 63;
  int bx, by, bz;
  swz_st(bx, by, bz, STX, STY);
  const int m0 = by * 64, n0 = bx * 64;
  const size_t kbeg = (size_t)bz * (size_t)KS;
  const int wm = (w >> 1) * 32, wn = (w & 1) * 32;

  f32x4 acc[2][2];
#pragma unroll
  for (int a = 0; a < 2; ++a)
#pragma unroll
    for (int b = 0; b < 2; ++b) acc[a][b] = (f32x4){0.f, 0.f, 0.f, 0.f};

  const int rsub = w * 8 + (l >> 3);
  const int ssrc = (l & 7) ^ (l >> 3);
  const int shalf = ssrc >> 2;
  const int schunk = ssrc & 3;
  const unsigned short* gA = (shalf ? Al : Ah) + (size_t)(m0 + rsub) * K + kbeg + schunk * 8;
  const unsigned short* gB = (shalf ? Bl : Bh) + (size_t)(n0 + rsub) * K + kbeg + schunk * 8;
  const size_t gstep = (size_t)32 * (size_t)K;
  const int db = w * 512;

  const int arow = (l & 15);
  const int slotH = ((l >> 4)) ^ (l & 7);
  const int slotL = (4 + (l >> 4)) ^ (l & 7);

  const int nk = KS >> 5;

  auto STAGE = [&](int buf, int kt) {
    const size_t ko = (size_t)kt * 32;
    unsigned short* da = &sA[buf][db];
    unsigned short* dbp = &sB[buf][db];
#pragma unroll
    for (int j = 0; j < 2; ++j) {
      gload16(gA + ko + (size_t)j * gstep, da + j * 2048);
      gload16(gB + ko + (size_t)j * gstep, dbp + j * 2048);
    }
  };

  STAGE(0, 0);
  __syncthreads();
  int cur = 0;

  for (int kt = 0; kt < nk; ++kt) {
    if (kt + 1 < nk) STAGE(cur ^ 1, kt + 1);
    const unsigned short* pa = &sA[cur][0];
    const unsigned short* pb = &sB[cur][0];
    s16x8 afh[2], afl[2], bfh[2], bfl[2];
#pragma unroll
    for (int mi = 0; mi < 2; ++mi) {
      const int rb = (wm + mi * 16 + arow) * 64;
      afh[mi] = *(const s16x8*)&pa[rb + slotH * 8];
      afl[mi] = *(const s16x8*)&pa[rb + slotL * 8];
    }
#pragma unroll
    for (int ni = 0; ni < 2; ++ni) {
      const int rb = (wn + ni * 16 + arow) * 64;
      bfh[ni] = *(const s16x8*)&pb[rb + slotH * 8];
      bfl[ni] = *(const s16x8*)&pb[rb + slotL * 8];
    }
#pragma unroll
    for (int mi = 0; mi < 2; ++mi)
#pragma unroll
      for (int ni = 0; ni < 2; ++ni) {
        acc[mi][ni] = __builtin_amdgcn_mfma_f32_16x16x32_bf16(afh[mi], bfh[ni], acc[mi][ni], 0, 0, 0);
        acc[mi][ni] = __builtin_amdgcn_mfma_f32_16x16x32_bf16(afh[mi], bfl[ni], acc[mi][ni], 0, 0, 0);
        acc[mi][ni] = __builtin_amdgcn_mfma_f32_16x16x32_bf16(afl[mi], bfh[ni], acc[mi][ni], 0, 0, 0);
      }
    __syncthreads();
    cur ^= 1;
  }

  const int colb = n0 + wn + (l & 15);
  const int rowb = m0 + wm + (l >> 4) * 4;

  if (EPI == 1) {
#pragma unroll
    for (int mi = 0; mi < 2; ++mi)
#pragma unroll
      for (int ni = 0; ni < 2; ++ni) {
        const int col = colb + ni * 16;
        const float bc = bias[col];
#pragma unroll
        for (int j = 0; j < 4; ++j) {
          const size_t idx = (size_t)(rowb + mi * 16 + j) * N + col;
          const float v = fast_tanh(acc[mi][ni][j] + bc);
          unsigned short hh, ll; split2(v, hh, ll);
          Oh[idx] = hh; Ol[idx] = ll;
        }
      }
  } else {
    float* dst = Part + (size_t)bz * (size_t)M * N;
#pragma unroll
    for (int mi = 0; mi < 2; ++mi)
#pragma unroll
      for (int ni = 0; ni < 2; ++ni) {
        const int col = colb + ni * 16;
#pragma unroll
        for (int j = 0; j < 4; ++j)
          dst[(size_t)(rowb + mi * 16 + j) * N + col] = acc[mi][ni][j];
      }
  }
}

// ---------------------------------------------------------------------------
// seq GEMM2 finish: F = sum_z Part[z]; E = X + sdt*F; [Eout=E];
// v = E [+ Dv]; X = v (+ hi/lo split); [Bout=v]
// ---------------------------------------------------------------------------
__global__ void reduce_axpy_k(const float* __restrict__ part, int S, int MN4,
    const float* __restrict__ tspan,
    float* __restrict__ Xf, unsigned short* __restrict__ Xh, unsigned short* __restrict__ Xl,
    const float* __restrict__ Dv, float* __restrict__ Bout, float* __restrict__ Eout)
{
  const int i = blockIdx.x * blockDim.x + threadIdx.x;
  if (i >= MN4) return;
  const float sdt = (tspan[1] - tspan[0]) * (1.0f / 7.0f);
  const size_t MN = (size_t)MN4 * 4;
  const size_t o = 4 * (size_t)i;
  f32x4 s = *(const f32x4*)(part + o);
  for (int z = 1; z < S; ++z) s += *(const f32x4*)(part + (size_t)z * MN + o);
  f32x4 e = *(const f32x4*)(Xf + o) + sdt * s;
  if (Eout) *(f32x4*)(Eout + o) = e;
  f32x4 v = e;
  if (Dv) v += *(const f32x4*)(Dv + o);
  *(f32x4*)(Xf + o) = v;
  u16x4 hh, ll;
#pragma unroll
  for (int j = 0; j < 4; ++j) { unsigned short h_, l_; split2(v[j], h_, l_); hh[j] = h_; ll[j] = l_; }
  *(u16x4*)(Xh + o) = hh;
  *(u16x4*)(Xl + o) = ll;
  if (Bout) *(f32x4*)(Bout + o) = v;
}

// ---------------------------------------------------------------------------
__global__ void axpy_split_k(
    float* __restrict__ dstF, unsigned short* __restrict__ dstH,
    unsigned short* __restrict__ dstL,
    const float* __restrict__ A, const float* __restrict__ Fv,
    float coef, int n4)
{
  for (int i = blockIdx.x * blockDim.x + threadIdx.x; i < n4;
       i += gridDim.x * blockDim.x) {
    const size_t o = 4 * (size_t)i;
    const f32x4 a = *(const f32x4*)(A + o);
    const f32x4 f = *(const f32x4*)(Fv + o);
    f32x4 v = a + coef * f;
    *(f32x4*)(dstF + o) = v;
    if (dstH) {
      u16x4 hh, ll;
#pragma unroll
      for (int j = 0; j < 4; ++j) { unsigned short h_, l_; split2(v[j], h_, l_); hh[j] = h_; ll[j] = l_; }
      *(u16x4*)(dstH + o) = hh;
      *(u16x4*)(dstL + o) = ll;
    }
  }
}

// ---------------------------------------------------------------------------
__global__ void transpose_split_k(const float* __restrict__ W,
                                  unsigned short* __restrict__ Th,
                                  unsigned short* __restrict__ Tl,
                                  int K, int N)
{
  __shared__ float t[32][33];
  const int tx = threadIdx.x & 31, ty = threadIdx.x >> 5;
  const int n0 = blockIdx.x * 32, k0 = blockIdx.y * 32;
#pragma unroll
  for (int r = 0; r < 4; ++r) {
    const int row = ty + r * 8;
    t[row][tx] = W[(size_t)(k0 + row) * N + n0 + tx];
  }
  __syncthreads();
#pragma unroll
  for (int r = 0; r < 4; ++r) {
    const int row = ty + r * 8;
    const float v = t[tx][row];
    unsigned short hh, ll; split2(v, hh, ll);
    const size_t idx = (size_t)(n0 + row) * K + k0 + tx;
    Th[idx] = hh; Tl[idx] = ll;
  }
}

// ---------------------------------------------------------------------------
extern "C" void kernel_launch(void* const* d_in, const int* in_sizes, int n_in,
                              void* d_out, int out_size, void* d_ws, size_t ws_size,
                              hipStream_t stream)
{
  const float* Bin   = (const float*)d_in[0];
  const float* tspan = (const float*)d_in[1];
  const float* W1    = (const float*)d_in[2];
  const float* b1    = (const float*)d_in[3];
  const float* W2    = (const float*)d_in[4];

  const int n = in_sizes[1];                 // 16
  const int h = in_sizes[3];                 // 4096
  const int d = in_sizes[2] / h;             // 1024
  const int batch = in_sizes[0] / (n * d);   // 256
  const int S = 7;                           // fine_steps-1
  const int MAXIT = 2;
  const size_t NB = (size_t)batch * d;

  float* Bw = (float*)d_out;

  uint8_t* wsb = (uint8_t*)d_ws;
  size_t off = 0;
  auto carve = [&](size_t bytes) -> void* {
    off = (off + 255) & ~(size_t)255;
    void* p = wsb + off; off += bytes; return p;
  };

  const size_t WH = (size_t)d * h;
  unsigned short* W1Th = (unsigned short*)carve(WH * 2);
  unsigned short* W1Tl = (unsigned short*)carve(WH * 2);
  unsigned short* W2Th = (unsigned short*)carve(WH * 2);
  unsigned short* W2Tl = (unsigned short*)carve(WH * 2);
  float* Dbuf = (float*)carve((size_t)(n - 1) * NB * 4);
  float* Eb   = (float*)carve((size_t)n * NB * 4);

  const int SPL2 = 4;
  float* Part = (float*)carve((size_t)SPL2 * NB * 4);

  const size_t per_node = NB * 20 + (size_t)batch * h * 4;
  int c;
  {
    size_t remb = ws_size > off + (1u << 20) ? ws_size - off - (1u << 20) : 0;
    c = (int)(remb / per_node);
    if (c < 1) c = 1;
    if (c > n - 1) c = n - 1;
  }
  const size_t CE = (size_t)c * NB;
  float*          Cst = (float*)carve(CE * 4);
  unsigned short* Csh = (unsigned short*)carve(CE * 2);
  unsigned short* Csl = (unsigned short*)carve(CE * 2);
  float*          Xf  = (float*)carve(CE * 4);
  unsigned short* Xh  = (unsigned short*)carve(CE * 2);
  unsigned short* Xl  = (unsigned short*)carve(CE * 2);
  float*          ACC = (float*)carve(CE * 4);
  unsigned short* Yh  = (unsigned short*)carve((size_t)c * batch * h * 2);
  unsigned short* Yl  = (unsigned short*)carve((size_t)c * batch * h * 2);
  unsigned short* XTh = Csh;   // time-disjoint with coarse sweep
  unsigned short* XTl = Csl;

  auto pickst = [](int g, int want) {
    int s = want;
    while (s > 1 && (g % s)) s >>= 1;
    return s;
  };
  auto ewg = [](size_t n4) -> int {
    size_t g = (n4 + 255) / 256;
    if (g > 2048) g = 2048; if (g < 1) g = 1;
    return (int)g;
  };
  auto axpy = [&](float* dF, unsigned short* dH, unsigned short* dL,
                  const float* A, const float* Fv, float coef, size_t ne) {
    const int n4 = (int)(ne / 4);
    axpy_split_k<<<ewg(n4), 256, 0, stream>>>(dF, dH, dL, A, Fv, coef, n4);
  };
  // vect g1: 256^2 when M>=3072 (underfill crossover), else 128^2.
  auto g1 = [&](const unsigned short* xh, const unsigned short* xl, int M) {
    if (M >= 3072) {
      const int gy = M / 256;
      gemm256_k<<<dim3(h / 256, gy, 1), 512, 0, stream>>>(
          xh, xl, W1Th, W1Tl, b1, Yh, Yl, M, h, d,
          pickst(h / 256, 2), pickst(gy, 2));
    } else {
      const int gy = M / 128;
      gemm_k<1><<<dim3(h / 128, gy, 1), 256, 0, stream>>>(
          xh, xl, W1Th, W1Tl, b1, Yh, Yl,
          nullptr, nullptr, nullptr, tspan, 0.f, 0.f, 0, M, h, d, d,
          pickst(h / 128, 8), pickst(gy, 4));
    }
  };
  auto g2rk = [&](int M, float a1, float a2, int add) {
    const int gy = M / 128;
    gemm_k<3><<<dim3(d / 128, gy, 1), 256, 0, stream>>>(
        Yh, Yl, W2Th, W2Tl, nullptr, XTh, XTl,
        Xf, ACC, nullptr, tspan, a1, a2, add, M, d, h, h,
        pickst(d / 128, 4), pickst(gy, 4));
  };
  auto g2ax = [&](int M, float* dF, unsigned short* dH, unsigned short* dL,
                  const float* Xin, float a1, float a2) {
    const int gy = M / 128;
    gemm_k<4><<<dim3(d / 128, gy, 1), 256, 0, stream>>>(
        Yh, Yl, W2Th, W2Tl, nullptr, dH, dL,
        Xin, nullptr, dF, tspan, a1, a2, 0, M, d, h, h,
        pickst(d / 128, 4), pickst(gy, 4));
  };

  // ---- prep ---------------------------------------------------------------
  hipMemcpyAsync(Bw, Bin, (size_t)n * NB * 4, hipMemcpyDeviceToDevice, stream);
  transpose_split_k<<<dim3(h / 32, d / 32), 256, 0, stream>>>(W1, W1Th, W1Tl, d, h);
  transpose_split_k<<<dim3(d / 32, h / 32), 256, 0, stream>>>(W2, W2Th, W2Tl, h, d);

  const int MN4d = (int)(NB / 4);

  // ---- Parareal outer loop ------------------------------------------------
  for (int i = 1; i <= MAXIT + 1; ++i) {
    const int rem = n - i;

    for (int base = 0; base < rem; base += c) {
      const int cc = (rem - base) < c ? (rem - base) : c;
      const int M = cc * batch;
      const size_t ne = (size_t)M * d;
      const int j0 = i - 1 + base;
      const float* src = Bw + (size_t)j0 * NB;

      if (i == 1) {
        // coarse Euler sweep (i>=2 reuses Eb from previous sequential phase)
        axpy(Cst, Csh, Csl, src, src, 0.f, ne);
        for (int s = 0; s < S; ++s) {
          g1(Csh, Csl, M);
          g2ax(M, Cst, Csh, Csl, Cst, 0.f, 1.f);
        }
      }
      // fine RK4 sweep
      axpy(Xf, Xh, Xl, src, src, 0.f, ne);
      for (int s = 0; s < S; ++s) {
        g1(Xh, Xl, M);   g2rk(M, 1.f / 6.f, 0.5f, 0);   // k1
        g1(XTh, XTl, M); g2rk(M, 1.f / 3.f, 0.5f, 1);   // k2
        g1(XTh, XTl, M); g2rk(M, 1.f / 3.f, 1.0f, 1);   // k3
        g1(XTh, XTl, M); g2ax(M, Xf, Xh, Xl, ACC, 0.f, 1.f / 6.f);  // k4
      }
      const float* Cref = (i == 1) ? Cst : (Eb + (size_t)j0 * NB);
      axpy(Dbuf + (size_t)base * NB, nullptr, nullptr, Xf, Cref, -1.f, ne);
    }

    // ---- sequential Parareal correction: 3 dispatches/substep, 64^2 -------
    const float* start = Bw + (size_t)(i - 1) * NB;
    axpy(Xf, Xh, Xl, start, start, 0.f, NB);
    for (int m = 0; m < rem; ++m) {
      for (int s = 0; s < S; ++s) {
        gemm64_k<1><<<dim3(h / 64, batch / 64, 1), 256, 0, stream>>>(
            Xh, Xl, W1Th, W1Tl, b1, nullptr, Yh, Yl, batch, h, d, d,
            pickst(h / 64, 8), pickst(batch / 64, 4));
        gemm64_k<2><<<dim3(d / 64, batch / 64, SPL2), 256, 0, stream>>>(
            Yh, Yl, W2Th, W2Tl, nullptr, Part, nullptr, nullptr,
            batch, d, h, h / SPL2,
            pickst(d / 64, 8), pickst(batch / 64, 4));
        const bool last = (s == S - 1);
        reduce_axpy_k<<<(MN4d + 255) / 256, 256, 0, stream>>>(
            Part, SPL2, MN4d, tspan, Xf, Xh, Xl,
            last ? Dbuf + (size_t)m * NB : nullptr,
            last ? Bw + (size_t)(i + m) * NB : nullptr,
            last ? Eb + (size_t)(i - 1 + m) * NB : nullptr);
      }
    }
  }
}

// Round 13
// 35493.268 us; speedup vs baseline: 1.0541x; 1.0179x over previous
//
#include <hip/hip_runtime.h>
#include <cstdint>
#include <cstddef>

// ---------------------------------------------------------------------------
// Parareal neural-ODE (MSZero_13761075216509)
// f(x) = tanh(x@W1 + b1) @ W2 ; fp32 via bf16 hi/lo 3-term split MFMA.
// R13: all MFMAs switched 16x16x32 -> 32x32x16 (2382 vs 2075 TF ceiling,
//      -17% matrix-pipe cycles at identical FLOPs/bytes/LDS traffic).
//      C/D mapping per m74/m101: col=lane&31, row=(reg&3)+8*(reg>>2)+4*(l>>5).
//      gemm256 path deleted (R11/R12 A/B: value-free). Everything else
//      identical to R12 (36.1ms best-class).
// ---------------------------------------------------------------------------

typedef __attribute__((ext_vector_type(4))) float f32x4;
typedef __attribute__((ext_vector_type(16))) float f32x16;
typedef __attribute__((ext_vector_type(8))) short s16x8;
typedef __attribute__((ext_vector_type(4))) unsigned short u16x4;

#define DEV __device__ __forceinline__

DEV unsigned short f2bf(float x) {
  union { float f; uint32_t u; } v; v.f = x;
  uint32_t r = v.u + 0x7FFFu + ((v.u >> 16) & 1u);   // RNE
  return (unsigned short)(r >> 16);
}
DEV float bf2f(unsigned short h) {
  union { uint32_t u; float f; } v; v.u = ((uint32_t)h) << 16; return v.f;
}
DEV void split2(float x, unsigned short &h, unsigned short &l) {
  h = f2bf(x);
  l = f2bf(x - bf2f(h));
}
DEV float fast_tanh(float z) {
  return 1.f - 2.f / (__expf(2.f * z) + 1.f);
}
DEV void gload16(const unsigned short* g, unsigned short* l) {
  __builtin_amdgcn_global_load_lds(
      (const __attribute__((address_space(1))) void*)g,
      (__attribute__((address_space(3))) void*)l, 16, 0, 0);
}

// bijective 2-D supertile XCD swizzle (R12, unchanged)
DEV void swz_st(int &bx, int &by, int &bz, int STX, int STY) {
  const int gx = gridDim.x, gy = gridDim.y, gz = gridDim.z;
  const int nwg = gx * gy * gz;
  const int lin = (blockIdx.z * gy + blockIdx.y) * gx + blockIdx.x;
  const int q = nwg >> 3, r = nwg & 7;
  const int x = lin & 7, j = lin >> 3;
  const int logical = (x < r ? x * (q + 1) : r * (q + 1) + (x - r) * q) + j;
  const int plane = gx * gy;
  bz = logical / plane;
  const int p = logical % plane;
  const int bps = STX * STY;
  const int sgy = gy / STY;
  const int stid = p / bps;
  const int wid = p % bps;
  const int stx = stid / sgy;
  const int sty = stid % sgy;
  bx = stx * STX + wid % STX;
  by = sty * STY + wid / STX;
}

// ---------------------------------------------------------------------------
// 128x128 GEMM, 32x32x16 MFMA. Wave tile 64x64 = 2x2 tiles of 32x32.
// A hi/lo bf16 [M][K], B pre-transposed hi/lo bf16 [N][K].
// LDS [128 rows][8 slots x 16B]/operand, phys slot = src ^ (row&7); dbuf,
// prefetch-issue-early. 24 MFMA(32x32x16)/wave/K-step (3-term x 4 tiles x 2kh)
// EPI=1: v=tanh(acc+bias[col]) -> Oh/Ol bf16
// EPI=3: rk-update: a=(add?ACC:X)+a1*sdt*acc -> ACC ; xt=X+a2*sdt*acc -> Oh/Ol
// EPI=4: axpy-update: v=Xin+(a1+a2*sdt)*acc -> Xout fp32 + Oh/Ol split
// ---------------------------------------------------------------------------
template<int EPI>
__global__ __launch_bounds__(256, 2) void gemm_k(
    const unsigned short* __restrict__ Ah, const unsigned short* __restrict__ Al,
    const unsigned short* __restrict__ Bh, const unsigned short* __restrict__ Bl,
    const float* __restrict__ bias,
    unsigned short* __restrict__ Oh, unsigned short* __restrict__ Ol,
    const float* __restrict__ Xin,
    float* __restrict__ ACCb,
    float* __restrict__ Xout,
    const float* __restrict__ tspan,
    float a1, float a2, int accAdd,
    int M, int N, int K, int KS, int STX, int STY)
{
  __shared__ unsigned short sA[2][128 * 64];
  __shared__ unsigned short sB[2][128 * 64];
  const int tid = threadIdx.x;
  const int w = tid >> 6, l = tid & 63;
  int bx, by, bz;
  swz_st(bx, by, bz, STX, STY);
  const int m0 = by * 128, n0 = bx * 128;
  const int wm = (w >> 1) * 64, wn = (w & 1) * 64;

  f32x16 acc[2][2];
#pragma unroll
  for (int a = 0; a < 2; ++a)
#pragma unroll
    for (int b = 0; b < 2; ++b)
#pragma unroll
      for (int r = 0; r < 16; ++r) acc[a][b][r] = 0.f;

  // staging (unchanged): call j of wave w -> row j*32 + w*8 + (l>>3),
  // phys slot l&7 holds src slot ssrc = (l&7) ^ (row&7)
  const int rsub = w * 8 + (l >> 3);
  const int ssrc = (l & 7) ^ (l >> 3);
  const int shalf = ssrc >> 2;
  const int schunk = ssrc & 3;
  const unsigned short* gA = (shalf ? Al : Ah) + (size_t)(m0 + rsub) * K + schunk * 8;
  const unsigned short* gB = (shalf ? Bl : Bh) + (size_t)(n0 + rsub) * K + schunk * 8;
  const size_t gstep = (size_t)32 * (size_t)K;
  const int db = w * 512;

  // 32x32x16 fragment geometry: lane holds op[row = l&31][k = kh*16+(l>>5)*8+i]
  // src slot = kh*2 + (l>>5) (+4 for lo); phys = src ^ (l&7) (row bases %8==0)
  const int arow = l & 31;
  const int kq = l >> 5;
  const int sH[2] = { (kq) ^ (l & 7), (2 + kq) ^ (l & 7) };
  const int sL[2] = { (4 + kq) ^ (l & 7), (6 + kq) ^ (l & 7) };

  const int nk = KS >> 5;

  auto STAGE = [&](int buf, int kt) {
    const size_t ko = (size_t)kt * 32;
    unsigned short* da = &sA[buf][db];
    unsigned short* dbp = &sB[buf][db];
#pragma unroll
    for (int j = 0; j < 4; ++j) {
      gload16(gA + ko + (size_t)j * gstep, da + j * 2048);
      gload16(gB + ko + (size_t)j * gstep, dbp + j * 2048);
    }
  };

  STAGE(0, 0);
  __syncthreads();
  int cur = 0;

  for (int kt = 0; kt < nk; ++kt) {
    if (kt + 1 < nk) STAGE(cur ^ 1, kt + 1);
    const unsigned short* pa = &sA[cur][0];
    const unsigned short* pb = &sB[cur][0];
#pragma unroll
    for (int kh = 0; kh < 2; ++kh) {
      const int sh = sH[kh], sl = sL[kh];
      s16x8 bfh[2], bfl[2];
#pragma unroll
      for (int ni = 0; ni < 2; ++ni) {
        const int rb = (wn + ni * 32 + arow) * 64;
        bfh[ni] = *(const s16x8*)&pb[rb + sh * 8];
        bfl[ni] = *(const s16x8*)&pb[rb + sl * 8];
      }
#pragma unroll
      for (int mi = 0; mi < 2; ++mi) {
        const int ra = (wm + mi * 32 + arow) * 64;
        const s16x8 afh = *(const s16x8*)&pa[ra + sh * 8];
        const s16x8 afl = *(const s16x8*)&pa[ra + sl * 8];
#pragma unroll
        for (int ni = 0; ni < 2; ++ni) {
          acc[mi][ni] = __builtin_amdgcn_mfma_f32_32x32x16_bf16(afh, bfh[ni], acc[mi][ni], 0, 0, 0);
          acc[mi][ni] = __builtin_amdgcn_mfma_f32_32x32x16_bf16(afh, bfl[ni], acc[mi][ni], 0, 0, 0);
          acc[mi][ni] = __builtin_amdgcn_mfma_f32_32x32x16_bf16(afl, bfh[ni], acc[mi][ni], 0, 0, 0);
        }
      }
    }
    __syncthreads();
    cur ^= 1;
  }

  // epilogue: col = n0+wn+ni*32+(l&31);
  // row = m0+wm+mi*32 + (r&3) + 8*(r>>2) + 4*(l>>5)   [m74/m101 verified]
  const int colb = n0 + wn + (l & 31);
  const int rowb = m0 + wm + 4 * (l >> 5);
  const float sdt = (EPI >= 3) ? (tspan[1] - tspan[0]) * (1.0f / 7.0f) : 0.f;

  if (EPI == 1) {
#pragma unroll
    for (int mi = 0; mi < 2; ++mi)
#pragma unroll
      for (int ni = 0; ni < 2; ++ni) {
        const int col = colb + ni * 32;
        const float bc = bias[col];
#pragma unroll
        for (int r = 0; r < 16; ++r) {
          const int row = rowb + mi * 32 + (r & 3) + 8 * (r >> 2);
          const size_t idx = (size_t)row * N + col;
          const float v = fast_tanh(acc[mi][ni][r] + bc);
          unsigned short hh, ll; split2(v, hh, ll);
          Oh[idx] = hh; Ol[idx] = ll;
        }
      }
  } else if (EPI == 3) {
    const float c1 = a1 * sdt, c2 = a2 * sdt;
#pragma unroll
    for (int mi = 0; mi < 2; ++mi)
#pragma unroll
      for (int ni = 0; ni < 2; ++ni) {
        const int col = colb + ni * 32;
#pragma unroll
        for (int r = 0; r < 16; ++r) {
          const int row = rowb + mi * 32 + (r & 3) + 8 * (r >> 2);
          const size_t idx = (size_t)row * N + col;
          const float f = acc[mi][ni][r];
          const float x = Xin[idx];
          const float a = (accAdd ? ACCb[idx] : x) + c1 * f;
          ACCb[idx] = a;
          const float xt = x + c2 * f;
          unsigned short hh, ll; split2(xt, hh, ll);
          Oh[idx] = hh; Ol[idx] = ll;
        }
      }
  } else {  // EPI == 4
    const float coef = a1 + a2 * sdt;
#pragma unroll
    for (int mi = 0; mi < 2; ++mi)
#pragma unroll
      for (int ni = 0; ni < 2; ++ni) {
        const int col = colb + ni * 32;
#pragma unroll
        for (int r = 0; r < 16; ++r) {
          const int row = rowb + mi * 32 + (r & 3) + 8 * (r >> 2);
          const size_t idx = (size_t)row * N + col;
          const float v = Xin[idx] + coef * acc[mi][ni][r];
          Xout[idx] = v;
          unsigned short hh, ll; split2(v, hh, ll);
          Oh[idx] = hh; Ol[idx] = ll;
        }
      }
  }
}

// ---------------------------------------------------------------------------
// 64x64 GEMM for the sequential phase, 32x32x16 MFMA (1 tile/wave, 6 MFMA
// per K-step). EPI=1: tanh(acc+bias)->Oh/Ol.  EPI=2: Part + bz*M*N partial.
// ---------------------------------------------------------------------------
template<int EPI>
__global__ __launch_bounds__(256, 2) void gemm64_k(
    const unsigned short* __restrict__ Ah, const unsigned short* __restrict__ Al,
    const unsigned short* __restrict__ Bh, const unsigned short* __restrict__ Bl,
    const float* __restrict__ bias,
    float* __restrict__ Part,
    unsigned short* __restrict__ Oh, unsigned short* __restrict__ Ol,
    int M, int N, int K, int KS, int STX, int STY)
{
  __shared__ unsigned short sA[2][64 * 64];
  __shared__ unsigned short sB[2][64 * 64];
  const int tid = threadIdx.x;
  const int w = tid >> 6, l = tid & 63;
  int bx, by, bz;
  swz_st(bx, by, bz, STX, STY);
  const int m0 = by * 64, n0 = bx * 64;
  const size_t kbeg = (size_t)bz * (size_t)KS;
  const int wm = (w >> 1) * 32, wn = (w & 1) * 32;

  f32x16 acc;
#pragma unroll
  for (int r = 0; r < 16; ++r) acc[r] = 0.f;

  const int rsub = w * 8 + (l >> 3);
  const int ssrc = (l & 7) ^ (l >> 3);
  const int shalf = ssrc >> 2;
  const int schunk = ssrc & 3;
  const unsigned short* gA = (shalf ? Al : Ah) + (size_t)(m0 + rsub) * K + kbeg + schunk * 8;
  const unsigned short* gB = (shalf ? Bl : Bh) + (size_t)(n0 + rsub) * K + kbeg + schunk * 8;
  const size_t gstep = (size_t)32 * (size_t)K;
  const int db = w * 512;

  const int arow = l & 31;
  const int kq = l >> 5;
  const int sH[2] = { (kq) ^ (l & 7), (2 + kq) ^ (l & 7) };
  const int sL[2] = { (4 + kq) ^ (l & 7), (6 + kq) ^ (l & 7) };

  const int nk = KS >> 5;

  auto STAGE = [&](int buf, int kt) {
    const size_t ko = (size_t)kt * 32;
    unsigned short* da = &sA[buf][db];
    unsigned short* dbp = &sB[buf][db];
#pragma unroll
    for (int j = 0; j < 2; ++j) {
      gload16(gA + ko + (size_t)j * gstep, da + j * 2048);
      gload16(gB + ko + (size_t)j * gstep, dbp + j * 2048);
    }
  };

  STAGE(0, 0);
  __syncthreads();
  int cur = 0;

  for (int kt = 0; kt < nk; ++kt) {
    if (kt + 1 < nk) STAGE(cur ^ 1, kt + 1);
    const unsigned short* pa = &sA[cur][0];
    const unsigned short* pb = &sB[cur][0];
#pragma unroll
    for (int kh = 0; kh < 2; ++kh) {
      const int sh = sH[kh], sl = sL[kh];
      const int rb = (wn + arow) * 64;
      const int ra = (wm + arow) * 64;
      const s16x8 bfh = *(const s16x8*)&pb[rb + sh * 8];
      const s16x8 bfl = *(const s16x8*)&pb[rb + sl * 8];
      const s16x8 afh = *(const s16x8*)&pa[ra + sh * 8];
      const s16x8 afl = *(const s16x8*)&pa[ra + sl * 8];
      acc = __builtin_amdgcn_mfma_f32_32x32x16_bf16(afh, bfh, acc, 0, 0, 0);
      acc = __builtin_amdgcn_mfma_f32_32x32x16_bf16(afh, bfl, acc, 0, 0, 0);
      acc = __builtin_amdgcn_mfma_f32_32x32x16_bf16(afl, bfh, acc, 0, 0, 0);
    }
    __syncthreads();
    cur ^= 1;
  }

  const int col = n0 + wn + (l & 31);
  const int rowb = m0 + wm + 4 * (l >> 5);

  if (EPI == 1) {
    const float bc = bias[col];
#pragma unroll
    for (int r = 0; r < 16; ++r) {
      const int row = rowb + (r & 3) + 8 * (r >> 2);
      const size_t idx = (size_t)row * N + col;
      const float v = fast_tanh(acc[r] + bc);
      unsigned short hh, ll; split2(v, hh, ll);
      Oh[idx] = hh; Ol[idx] = ll;
    }
  } else {
    float* dst = Part + (size_t)bz * (size_t)M * N;
#pragma unroll
    for (int r = 0; r < 16; ++r) {
      const int row = rowb + (r & 3) + 8 * (r >> 2);
      dst[(size_t)row * N + col] = acc[r];
    }
  }
}

// ---------------------------------------------------------------------------
// seq GEMM2 finish: F = sum_z Part[z]; E = X + sdt*F; [Eout=E];
// v = E [+ Dv]; X = v (+ hi/lo split); [Bout=v]
// ---------------------------------------------------------------------------
__global__ void reduce_axpy_k(const float* __restrict__ part, int S, int MN4,
    const float* __restrict__ tspan,
    float* __restrict__ Xf, unsigned short* __restrict__ Xh, unsigned short* __restrict__ Xl,
    const float* __restrict__ Dv, float* __restrict__ Bout, float* __restrict__ Eout)
{
  const int i = blockIdx.x * blockDim.x + threadIdx.x;
  if (i >= MN4) return;
  const float sdt = (tspan[1] - tspan[0]) * (1.0f / 7.0f);
  const size_t MN = (size_t)MN4 * 4;
  const size_t o = 4 * (size_t)i;
  f32x4 s = *(const f32x4*)(part + o);
  for (int z = 1; z < S; ++z) s += *(const f32x4*)(part + (size_t)z * MN + o);
  f32x4 e = *(const f32x4*)(Xf + o) + sdt * s;
  if (Eout) *(f32x4*)(Eout + o) = e;
  f32x4 v = e;
  if (Dv) v += *(const f32x4*)(Dv + o);
  *(f32x4*)(Xf + o) = v;
  u16x4 hh, ll;
#pragma unroll
  for (int j = 0; j < 4; ++j) { unsigned short h_, l_; split2(v[j], h_, l_); hh[j] = h_; ll[j] = l_; }
  *(u16x4*)(Xh + o) = hh;
  *(u16x4*)(Xl + o) = ll;
  if (Bout) *(f32x4*)(Bout + o) = v;
}

// ---------------------------------------------------------------------------
__global__ void axpy_split_k(
    float* __restrict__ dstF, unsigned short* __restrict__ dstH,
    unsigned short* __restrict__ dstL,
    const float* __restrict__ A, const float* __restrict__ Fv,
    float coef, int n4)
{
  for (int i = blockIdx.x * blockDim.x + threadIdx.x; i < n4;
       i += gridDim.x * blockDim.x) {
    const size_t o = 4 * (size_t)i;
    const f32x4 a = *(const f32x4*)(A + o);
    const f32x4 f = *(const f32x4*)(Fv + o);
    f32x4 v = a + coef * f;
    *(f32x4*)(dstF + o) = v;
    if (dstH) {
      u16x4 hh, ll;
#pragma unroll
      for (int j = 0; j < 4; ++j) { unsigned short h_, l_; split2(v[j], h_, l_); hh[j] = h_; ll[j] = l_; }
      *(u16x4*)(dstH + o) = hh;
      *(u16x4*)(dstL + o) = ll;
    }
  }
}

// ---------------------------------------------------------------------------
__global__ void transpose_split_k(const float* __restrict__ W,
                                  unsigned short* __restrict__ Th,
                                  unsigned short* __restrict__ Tl,
                                  int K, int N)
{
  __shared__ float t[32][33];
  const int tx = threadIdx.x & 31, ty = threadIdx.x >> 5;
  const int n0 = blockIdx.x * 32, k0 = blockIdx.y * 32;
#pragma unroll
  for (int r = 0; r < 4; ++r) {
    const int row = ty + r * 8;
    t[row][tx] = W[(size_t)(k0 + row) * N + n0 + tx];
  }
  __syncthreads();
#pragma unroll
  for (int r = 0; r < 4; ++r) {
    const int row = ty + r * 8;
    const float v = t[tx][row];
    unsigned short hh, ll; split2(v, hh, ll);
    const size_t idx = (size_t)(n0 + row) * K + k0 + tx;
    Th[idx] = hh; Tl[idx] = ll;
  }
}

// ---------------------------------------------------------------------------
extern "C" void kernel_launch(void* const* d_in, const int* in_sizes, int n_in,
                              void* d_out, int out_size, void* d_ws, size_t ws_size,
                              hipStream_t stream)
{
  const float* Bin   = (const float*)d_in[0];
  const float* tspan = (const float*)d_in[1];
  const float* W1    = (const float*)d_in[2];
  const float* b1    = (const float*)d_in[3];
  const float* W2    = (const float*)d_in[4];

  const int n = in_sizes[1];                 // 16
  const int h = in_sizes[3];                 // 4096
  const int d = in_sizes[2] / h;             // 1024
  const int batch = in_sizes[0] / (n * d);   // 256
  const int S = 7;                           // fine_steps-1
  const int MAXIT = 2;
  const size_t NB = (size_t)batch * d;

  float* Bw = (float*)d_out;

  uint8_t* wsb = (uint8_t*)d_ws;
  size_t off = 0;
  auto carve = [&](size_t bytes) -> void* {
    off = (off + 255) & ~(size_t)255;
    void* p = wsb + off; off += bytes; return p;
  };

  const size_t WH = (size_t)d * h;
  unsigned short* W1Th = (unsigned short*)carve(WH * 2);
  unsigned short* W1Tl = (unsigned short*)carve(WH * 2);
  unsigned short* W2Th = (unsigned short*)carve(WH * 2);
  unsigned short* W2Tl = (unsigned short*)carve(WH * 2);
  float* Dbuf = (float*)carve((size_t)(n - 1) * NB * 4);
  float* Eb   = (float*)carve((size_t)n * NB * 4);

  const int SPL2 = 4;
  float* Part = (float*)carve((size_t)SPL2 * NB * 4);

  const size_t per_node = NB * 20 + (size_t)batch * h * 4;
  int c;
  {
    size_t remb = ws_size > off + (1u << 20) ? ws_size - off - (1u << 20) : 0;
    c = (int)(remb / per_node);
    if (c < 1) c = 1;
    if (c > n - 1) c = n - 1;
  }
  const size_t CE = (size_t)c * NB;
  float*          Cst = (float*)carve(CE * 4);
  unsigned short* Csh = (unsigned short*)carve(CE * 2);
  unsigned short* Csl = (unsigned short*)carve(CE * 2);
  float*          Xf  = (float*)carve(CE * 4);
  unsigned short* Xh  = (unsigned short*)carve(CE * 2);
  unsigned short* Xl  = (unsigned short*)carve(CE * 2);
  float*          ACC = (float*)carve(CE * 4);
  unsigned short* Yh  = (unsigned short*)carve((size_t)c * batch * h * 2);
  unsigned short* Yl  = (unsigned short*)carve((size_t)c * batch * h * 2);
  unsigned short* XTh = Csh;   // time-disjoint with coarse sweep
  unsigned short* XTl = Csl;

  auto pickst = [](int g, int want) {
    int s = want;
    while (s > 1 && (g % s)) s >>= 1;
    return s;
  };
  auto ewg = [](size_t n4) -> int {
    size_t g = (n4 + 255) / 256;
    if (g > 2048) g = 2048; if (g < 1) g = 1;
    return (int)g;
  };
  auto axpy = [&](float* dF, unsigned short* dH, unsigned short* dL,
                  const float* A, const float* Fv, float coef, size_t ne) {
    const int n4 = (int)(ne / 4);
    axpy_split_k<<<ewg(n4), 256, 0, stream>>>(dF, dH, dL, A, Fv, coef, n4);
  };
  auto g1 = [&](const unsigned short* xh, const unsigned short* xl, int M) {
    const int gy = M / 128;
    gemm_k<1><<<dim3(h / 128, gy, 1), 256, 0, stream>>>(
        xh, xl, W1Th, W1Tl, b1, Yh, Yl,
        nullptr, nullptr, nullptr, tspan, 0.f, 0.f, 0, M, h, d, d,
        pickst(h / 128, 8), pickst(gy, 4));
  };
  auto g2rk = [&](int M, float a1, float a2, int add) {
    const int gy = M / 128;
    gemm_k<3><<<dim3(d / 128, gy, 1), 256, 0, stream>>>(
        Yh, Yl, W2Th, W2Tl, nullptr, XTh, XTl,
        Xf, ACC, nullptr, tspan, a1, a2, add, M, d, h, h,
        pickst(d / 128, 4), pickst(gy, 4));
  };
  auto g2ax = [&](int M, float* dF, unsigned short* dH, unsigned short* dL,
                  const float* Xin, float a1, float a2) {
    const int gy = M / 128;
    gemm_k<4><<<dim3(d / 128, gy, 1), 256, 0, stream>>>(
        Yh, Yl, W2Th, W2Tl, nullptr, dH, dL,
        Xin, nullptr, dF, tspan, a1, a2, 0, M, d, h, h,
        pickst(d / 128, 4), pickst(gy, 4));
  };

  // ---- prep ---------------------------------------------------------------
  hipMemcpyAsync(Bw, Bin, (size_t)n * NB * 4, hipMemcpyDeviceToDevice, stream);
  transpose_split_k<<<dim3(h / 32, d / 32), 256, 0, stream>>>(W1, W1Th, W1Tl, d, h);
  transpose_split_k<<<dim3(d / 32, h / 32), 256, 0, stream>>>(W2, W2Th, W2Tl, h, d);

  const int MN4d = (int)(NB / 4);

  // ---- Parareal outer loop ------------------------------------------------
  for (int i = 1; i <= MAXIT + 1; ++i) {
    const int rem = n - i;

    for (int base = 0; base < rem; base += c) {
      const int cc = (rem - base) < c ? (rem - base) : c;
      const int M = cc * batch;
      const size_t ne = (size_t)M * d;
      const int j0 = i - 1 + base;
      const float* src = Bw + (size_t)j0 * NB;

      if (i == 1) {
        // coarse Euler sweep (i>=2 reuses Eb from previous sequential phase)
        axpy(Cst, Csh, Csl, src, src, 0.f, ne);
        for (int s = 0; s < S; ++s) {
          g1(Csh, Csl, M);
          g2ax(M, Cst, Csh, Csl, Cst, 0.f, 1.f);
        }
      }
      // fine RK4 sweep
      axpy(Xf, Xh, Xl, src, src, 0.f, ne);
      for (int s = 0; s < S; ++s) {
        g1(Xh, Xl, M);   g2rk(M, 1.f / 6.f, 0.5f, 0);   // k1
        g1(XTh, XTl, M); g2rk(M, 1.f / 3.f, 0.5f, 1);   // k2
        g1(XTh, XTl, M); g2rk(M, 1.f / 3.f, 1.0f, 1);   // k3
        g1(XTh, XTl, M); g2ax(M, Xf, Xh, Xl, ACC, 0.f, 1.f / 6.f);  // k4
      }
      const float* Cref = (i == 1) ? Cst : (Eb + (size_t)j0 * NB);
      axpy(Dbuf + (size_t)base * NB, nullptr, nullptr, Xf, Cref, -1.f, ne);
    }

    // ---- sequential Parareal correction: 3 dispatches/substep, 64^2 -------
    const float* start = Bw + (size_t)(i - 1) * NB;
    axpy(Xf, Xh, Xl, start, start, 0.f, NB);
    for (int m = 0; m < rem; ++m) {
      for (int s = 0; s < S; ++s) {
        gemm64_k<1><<<dim3(h / 64, batch / 64, 1), 256, 0, stream>>>(
            Xh, Xl, W1Th, W1Tl, b1, nullptr, Yh, Yl, batch, h, d, d,
            pickst(h / 64, 8), pickst(batch / 64, 4));
        gemm64_k<2><<<dim3(d / 64, batch / 64, SPL2), 256, 0, stream>>>(
            Yh, Yl, W2Th, W2Tl, nullptr, Part, nullptr, nullptr,
            batch, d, h, h / SPL2,
            pickst(d / 64, 8), pickst(batch / 64, 4));
        const bool last = (s == S - 1);
        reduce_axpy_k<<<(MN4d + 255) / 256, 256, 0, stream>>>(
            Part, SPL2, MN4d, tspan, Xf, Xh, Xl,
            last ? Dbuf + (size_t)m * NB : nullptr,
            last ? Bw + (size_t)(i + m) * NB : nullptr,
            last ? Eb + (size_t)(i - 1 + m) * NB : nullptr);
      }
    }
  }
}

// Round 14
// 35249.609 us; speedup vs baseline: 1.0614x; 1.0069x over previous
//
#include <hip/hip_runtime.h>
#include <cstdint>
#include <cstddef>

// ---------------------------------------------------------------------------
// Parareal neural-ODE (MSZero_13761075216509)
// f(x) = tanh(x@W1 + b1) @ W2 ; fp32 via bf16 hi/lo 3-term split MFMA.
// R14: R13 (35.5ms) + workspace diet: Cst deleted (coarse Euler state lives
//      directly in its Dbuf slot, R4-proven), per-node scratch 9.4->8.4MB.
//      Rationale: a z=1 GEMM dispatch costs its K-chain regardless of M, so
//      G2's ~25-30us is fixed per CHUNK-f-eval; chunk count scales 1/c and c
//      is ws-limited. Every freed byte -> wider c -> fewer chunk-f-evals.
//      Kernels byte-identical to R13.
// ---------------------------------------------------------------------------

typedef __attribute__((ext_vector_type(4))) float f32x4;
typedef __attribute__((ext_vector_type(16))) float f32x16;
typedef __attribute__((ext_vector_type(8))) short s16x8;
typedef __attribute__((ext_vector_type(4))) unsigned short u16x4;

#define DEV __device__ __forceinline__

DEV unsigned short f2bf(float x) {
  union { float f; uint32_t u; } v; v.f = x;
  uint32_t r = v.u + 0x7FFFu + ((v.u >> 16) & 1u);   // RNE
  return (unsigned short)(r >> 16);
}
DEV float bf2f(unsigned short h) {
  union { uint32_t u; float f; } v; v.u = ((uint32_t)h) << 16; return v.f;
}
DEV void split2(float x, unsigned short &h, unsigned short &l) {
  h = f2bf(x);
  l = f2bf(x - bf2f(h));
}
DEV float fast_tanh(float z) {
  return 1.f - 2.f / (__expf(2.f * z) + 1.f);
}
DEV void gload16(const unsigned short* g, unsigned short* l) {
  __builtin_amdgcn_global_load_lds(
      (const __attribute__((address_space(1))) void*)g,
      (__attribute__((address_space(3))) void*)l, 16, 0, 0);
}

// bijective 2-D supertile XCD swizzle (R12, unchanged)
DEV void swz_st(int &bx, int &by, int &bz, int STX, int STY) {
  const int gx = gridDim.x, gy = gridDim.y, gz = gridDim.z;
  const int nwg = gx * gy * gz;
  const int lin = (blockIdx.z * gy + blockIdx.y) * gx + blockIdx.x;
  const int q = nwg >> 3, r = nwg & 7;
  const int x = lin & 7, j = lin >> 3;
  const int logical = (x < r ? x * (q + 1) : r * (q + 1) + (x - r) * q) + j;
  const int plane = gx * gy;
  bz = logical / plane;
  const int p = logical % plane;
  const int bps = STX * STY;
  const int sgy = gy / STY;
  const int stid = p / bps;
  const int wid = p % bps;
  const int stx = stid / sgy;
  const int sty = stid % sgy;
  bx = stx * STX + wid % STX;
  by = sty * STY + wid / STX;
}

// ---------------------------------------------------------------------------
// 128x128 GEMM, 32x32x16 MFMA (R13, unchanged). Wave tile 64x64 = 2x2 of 32².
// EPI=1: v=tanh(acc+bias[col]) -> Oh/Ol bf16
// EPI=3: rk-update: a=(add?ACC:X)+a1*sdt*acc -> ACC ; xt=X+a2*sdt*acc -> Oh/Ol
// EPI=4: axpy-update: v=Xin+(a1+a2*sdt)*acc -> Xout fp32 + Oh/Ol split
// ---------------------------------------------------------------------------
template<int EPI>
__global__ __launch_bounds__(256, 2) void gemm_k(
    const unsigned short* __restrict__ Ah, const unsigned short* __restrict__ Al,
    const unsigned short* __restrict__ Bh, const unsigned short* __restrict__ Bl,
    const float* __restrict__ bias,
    unsigned short* __restrict__ Oh, unsigned short* __restrict__ Ol,
    const float* __restrict__ Xin,
    float* __restrict__ ACCb,
    float* __restrict__ Xout,
    const float* __restrict__ tspan,
    float a1, float a2, int accAdd,
    int M, int N, int K, int KS, int STX, int STY)
{
  __shared__ unsigned short sA[2][128 * 64];
  __shared__ unsigned short sB[2][128 * 64];
  const int tid = threadIdx.x;
  const int w = tid >> 6, l = tid & 63;
  int bx, by, bz;
  swz_st(bx, by, bz, STX, STY);
  const int m0 = by * 128, n0 = bx * 128;
  const int wm = (w >> 1) * 64, wn = (w & 1) * 64;

  f32x16 acc[2][2];
#pragma unroll
  for (int a = 0; a < 2; ++a)
#pragma unroll
    for (int b = 0; b < 2; ++b)
#pragma unroll
      for (int r = 0; r < 16; ++r) acc[a][b][r] = 0.f;

  const int rsub = w * 8 + (l >> 3);
  const int ssrc = (l & 7) ^ (l >> 3);
  const int shalf = ssrc >> 2;
  const int schunk = ssrc & 3;
  const unsigned short* gA = (shalf ? Al : Ah) + (size_t)(m0 + rsub) * K + schunk * 8;
  const unsigned short* gB = (shalf ? Bl : Bh) + (size_t)(n0 + rsub) * K + schunk * 8;
  const size_t gstep = (size_t)32 * (size_t)K;
  const int db = w * 512;

  const int arow = l & 31;
  const int kq = l >> 5;
  const int sH[2] = { (kq) ^ (l & 7), (2 + kq) ^ (l & 7) };
  const int sL[2] = { (4 + kq) ^ (l & 7), (6 + kq) ^ (l & 7) };

  const int nk = KS >> 5;

  auto STAGE = [&](int buf, int kt) {
    const size_t ko = (size_t)kt * 32;
    unsigned short* da = &sA[buf][db];
    unsigned short* dbp = &sB[buf][db];
#pragma unroll
    for (int j = 0; j < 4; ++j) {
      gload16(gA + ko + (size_t)j * gstep, da + j * 2048);
      gload16(gB + ko + (size_t)j * gstep, dbp + j * 2048);
    }
  };

  STAGE(0, 0);
  __syncthreads();
  int cur = 0;

  for (int kt = 0; kt < nk; ++kt) {
    if (kt + 1 < nk) STAGE(cur ^ 1, kt + 1);
    const unsigned short* pa = &sA[cur][0];
    const unsigned short* pb = &sB[cur][0];
#pragma unroll
    for (int kh = 0; kh < 2; ++kh) {
      const int sh = sH[kh], sl = sL[kh];
      s16x8 bfh[2], bfl[2];
#pragma unroll
      for (int ni = 0; ni < 2; ++ni) {
        const int rb = (wn + ni * 32 + arow) * 64;
        bfh[ni] = *(const s16x8*)&pb[rb + sh * 8];
        bfl[ni] = *(const s16x8*)&pb[rb + sl * 8];
      }
#pragma unroll
      for (int mi = 0; mi < 2; ++mi) {
        const int ra = (wm + mi * 32 + arow) * 64;
        const s16x8 afh = *(const s16x8*)&pa[ra + sh * 8];
        const s16x8 afl = *(const s16x8*)&pa[ra + sl * 8];
#pragma unroll
        for (int ni = 0; ni < 2; ++ni) {
          acc[mi][ni] = __builtin_amdgcn_mfma_f32_32x32x16_bf16(afh, bfh[ni], acc[mi][ni], 0, 0, 0);
          acc[mi][ni] = __builtin_amdgcn_mfma_f32_32x32x16_bf16(afh, bfl[ni], acc[mi][ni], 0, 0, 0);
          acc[mi][ni] = __builtin_amdgcn_mfma_f32_32x32x16_bf16(afl, bfh[ni], acc[mi][ni], 0, 0, 0);
        }
      }
    }
    __syncthreads();
    cur ^= 1;
  }

  const int colb = n0 + wn + (l & 31);
  const int rowb = m0 + wm + 4 * (l >> 5);
  const float sdt = (EPI >= 3) ? (tspan[1] - tspan[0]) * (1.0f / 7.0f) : 0.f;

  if (EPI == 1) {
#pragma unroll
    for (int mi = 0; mi < 2; ++mi)
#pragma unroll
      for (int ni = 0; ni < 2; ++ni) {
        const int col = colb + ni * 32;
        const float bc = bias[col];
#pragma unroll
        for (int r = 0; r < 16; ++r) {
          const int row = rowb + mi * 32 + (r & 3) + 8 * (r >> 2);
          const size_t idx = (size_t)row * N + col;
          const float v = fast_tanh(acc[mi][ni][r] + bc);
          unsigned short hh, ll; split2(v, hh, ll);
          Oh[idx] = hh; Ol[idx] = ll;
        }
      }
  } else if (EPI == 3) {
    const float c1 = a1 * sdt, c2 = a2 * sdt;
#pragma unroll
    for (int mi = 0; mi < 2; ++mi)
#pragma unroll
      for (int ni = 0; ni < 2; ++ni) {
        const int col = colb + ni * 32;
#pragma unroll
        for (int r = 0; r < 16; ++r) {
          const int row = rowb + mi * 32 + (r & 3) + 8 * (r >> 2);
          const size_t idx = (size_t)row * N + col;
          const float f = acc[mi][ni][r];
          const float x = Xin[idx];
          const float a = (accAdd ? ACCb[idx] : x) + c1 * f;
          ACCb[idx] = a;
          const float xt = x + c2 * f;
          unsigned short hh, ll; split2(xt, hh, ll);
          Oh[idx] = hh; Ol[idx] = ll;
        }
      }
  } else {  // EPI == 4
    const float coef = a1 + a2 * sdt;
#pragma unroll
    for (int mi = 0; mi < 2; ++mi)
#pragma unroll
      for (int ni = 0; ni < 2; ++ni) {
        const int col = colb + ni * 32;
#pragma unroll
        for (int r = 0; r < 16; ++r) {
          const int row = rowb + mi * 32 + (r & 3) + 8 * (r >> 2);
          const size_t idx = (size_t)row * N + col;
          const float v = Xin[idx] + coef * acc[mi][ni][r];
          Xout[idx] = v;
          unsigned short hh, ll; split2(v, hh, ll);
          Oh[idx] = hh; Ol[idx] = ll;
        }
      }
  }
}

// ---------------------------------------------------------------------------
// 64x64 GEMM for the sequential phase, 32x32x16 MFMA (R13, unchanged).
// EPI=1: tanh(acc+bias)->Oh/Ol.  EPI=2: Part + bz*M*N partial.
// ---------------------------------------------------------------------------
template<int EPI>
__global__ __launch_bounds__(256, 2) void gemm64_k(
    const unsigned short* __restrict__ Ah, const unsigned short* __restrict__ Al,
    const unsigned short* __restrict__ Bh, const unsigned short* __restrict__ Bl,
    const float* __restrict__ bias,
    float* __restrict__ Part,
    unsigned short* __restrict__ Oh, unsigned short* __restrict__ Ol,
    int M, int N, int K, int KS, int STX, int STY)
{
  __shared__ unsigned short sA[2][64 * 64];
  __shared__ unsigned short sB[2][64 * 64];
  const int tid = threadIdx.x;
  const int w = tid >> 6, l = tid & 63;
  int bx, by, bz;
  swz_st(bx, by, bz, STX, STY);
  const int m0 = by * 64, n0 = bx * 64;
  const size_t kbeg = (size_t)bz * (size_t)KS;
  const int wm = (w >> 1) * 32, wn = (w & 1) * 32;

  f32x16 acc;
#pragma unroll
  for (int r = 0; r < 16; ++r) acc[r] = 0.f;

  const int rsub = w * 8 + (l >> 3);
  const int ssrc = (l & 7) ^ (l >> 3);
  const int shalf = ssrc >> 2;
  const int schunk = ssrc & 3;
  const unsigned short* gA = (shalf ? Al : Ah) + (size_t)(m0 + rsub) * K + kbeg + schunk * 8;
  const unsigned short* gB = (shalf ? Bl : Bh) + (size_t)(n0 + rsub) * K + kbeg + schunk * 8;
  const size_t gstep = (size_t)32 * (size_t)K;
  const int db = w * 512;

  const int arow = l & 31;
  const int kq = l >> 5;
  const int sH[2] = { (kq) ^ (l & 7), (2 + kq) ^ (l & 7) };
  const int sL[2] = { (4 + kq) ^ (l & 7), (6 + kq) ^ (l & 7) };

  const int nk = KS >> 5;

  auto STAGE = [&](int buf, int kt) {
    const size_t ko = (size_t)kt * 32;
    unsigned short* da = &sA[buf][db];
    unsigned short* dbp = &sB[buf][db];
#pragma unroll
    for (int j = 0; j < 2; ++j) {
      gload16(gA + ko + (size_t)j * gstep, da + j * 2048);
      gload16(gB + ko + (size_t)j * gstep, dbp + j * 2048);
    }
  };

  STAGE(0, 0);
  __syncthreads();
  int cur = 0;

  for (int kt = 0; kt < nk; ++kt) {
    if (kt + 1 < nk) STAGE(cur ^ 1, kt + 1);
    const unsigned short* pa = &sA[cur][0];
    const unsigned short* pb = &sB[cur][0];
#pragma unroll
    for (int kh = 0; kh < 2; ++kh) {
      const int sh = sH[kh], sl = sL[kh];
      const int rb = (wn + arow) * 64;
      const int ra = (wm + arow) * 64;
      const s16x8 bfh = *(const s16x8*)&pb[rb + sh * 8];
      const s16x8 bfl = *(const s16x8*)&pb[rb + sl * 8];
      const s16x8 afh = *(const s16x8*)&pa[ra + sh * 8];
      const s16x8 afl = *(const s16x8*)&pa[ra + sl * 8];
      acc = __builtin_amdgcn_mfma_f32_32x32x16_bf16(afh, bfh, acc, 0, 0, 0);
      acc = __builtin_amdgcn_mfma_f32_32x32x16_bf16(afh, bfl, acc, 0, 0, 0);
      acc = __builtin_amdgcn_mfma_f32_32x32x16_bf16(afl, bfh, acc, 0, 0, 0);
    }
    __syncthreads();
    cur ^= 1;
  }

  const int col = n0 + wn + (l & 31);
  const int rowb = m0 + wm + 4 * (l >> 5);

  if (EPI == 1) {
    const float bc = bias[col];
#pragma unroll
    for (int r = 0; r < 16; ++r) {
      const int row = rowb + (r & 3) + 8 * (r >> 2);
      const size_t idx = (size_t)row * N + col;
      const float v = fast_tanh(acc[r] + bc);
      unsigned short hh, ll; split2(v, hh, ll);
      Oh[idx] = hh; Ol[idx] = ll;
    }
  } else {
    float* dst = Part + (size_t)bz * (size_t)M * N;
#pragma unroll
    for (int r = 0; r < 16; ++r) {
      const int row = rowb + (r & 3) + 8 * (r >> 2);
      dst[(size_t)row * N + col] = acc[r];
    }
  }
}

// ---------------------------------------------------------------------------
// seq GEMM2 finish: F = sum_z Part[z]; E = X + sdt*F; [Eout=E];
// v = E [+ Dv]; X = v (+ hi/lo split); [Bout=v]
// ---------------------------------------------------------------------------
__global__ void reduce_axpy_k(const float* __restrict__ part, int S, int MN4,
    const float* __restrict__ tspan,
    float* __restrict__ Xf, unsigned short* __restrict__ Xh, unsigned short* __restrict__ Xl,
    const float* __restrict__ Dv, float* __restrict__ Bout, float* __restrict__ Eout)
{
  const int i = blockIdx.x * blockDim.x + threadIdx.x;
  if (i >= MN4) return;
  const float sdt = (tspan[1] - tspan[0]) * (1.0f / 7.0f);
  const size_t MN = (size_t)MN4 * 4;
  const size_t o = 4 * (size_t)i;
  f32x4 s = *(const f32x4*)(part + o);
  for (int z = 1; z < S; ++z) s += *(const f32x4*)(part + (size_t)z * MN + o);
  f32x4 e = *(const f32x4*)(Xf + o) + sdt * s;
  if (Eout) *(f32x4*)(Eout + o) = e;
  f32x4 v = e;
  if (Dv) v += *(const f32x4*)(Dv + o);
  *(f32x4*)(Xf + o) = v;
  u16x4 hh, ll;
#pragma unroll
  for (int j = 0; j < 4; ++j) { unsigned short h_, l_; split2(v[j], h_, l_); hh[j] = h_; ll[j] = l_; }
  *(u16x4*)(Xh + o) = hh;
  *(u16x4*)(Xl + o) = ll;
  if (Bout) *(f32x4*)(Bout + o) = v;
}

// ---------------------------------------------------------------------------
__global__ void axpy_split_k(
    float* __restrict__ dstF, unsigned short* __restrict__ dstH,
    unsigned short* __restrict__ dstL,
    const float* __restrict__ A, const float* __restrict__ Fv,
    float coef, int n4)
{
  for (int i = blockIdx.x * blockDim.x + threadIdx.x; i < n4;
       i += gridDim.x * blockDim.x) {
    const size_t o = 4 * (size_t)i;
    const f32x4 a = *(const f32x4*)(A + o);
    const f32x4 f = *(const f32x4*)(Fv + o);
    f32x4 v = a + coef * f;
    *(f32x4*)(dstF + o) = v;
    if (dstH) {
      u16x4 hh, ll;
#pragma unroll
      for (int j = 0; j < 4; ++j) { unsigned short h_, l_; split2(v[j], h_, l_); hh[j] = h_; ll[j] = l_; }
      *(u16x4*)(dstH + o) = hh;
      *(u16x4*)(dstL + o) = ll;
    }
  }
}

// ---------------------------------------------------------------------------
__global__ void transpose_split_k(const float* __restrict__ W,
                                  unsigned short* __restrict__ Th,
                                  unsigned short* __restrict__ Tl,
                                  int K, int N)
{
  __shared__ float t[32][33];
  const int tx = threadIdx.x & 31, ty = threadIdx.x >> 5;
  const int n0 = blockIdx.x * 32, k0 = blockIdx.y * 32;
#pragma unroll
  for (int r = 0; r < 4; ++r) {
    const int row = ty + r * 8;
    t[row][tx] = W[(size_t)(k0 + row) * N + n0 + tx];
  }
  __syncthreads();
#pragma unroll
  for (int r = 0; r < 4; ++r) {
    const int row = ty + r * 8;
    const float v = t[tx][row];
    unsigned short hh, ll; split2(v, hh, ll);
    const size_t idx = (size_t)(n0 + row) * K + k0 + tx;
    Th[idx] = hh; Tl[idx] = ll;
  }
}

// ---------------------------------------------------------------------------
extern "C" void kernel_launch(void* const* d_in, const int* in_sizes, int n_in,
                              void* d_out, int out_size, void* d_ws, size_t ws_size,
                              hipStream_t stream)
{
  const float* Bin   = (const float*)d_in[0];
  const float* tspan = (const float*)d_in[1];
  const float* W1    = (const float*)d_in[2];
  const float* b1    = (const float*)d_in[3];
  const float* W2    = (const float*)d_in[4];

  const int n = in_sizes[1];                 // 16
  const int h = in_sizes[3];                 // 4096
  const int d = in_sizes[2] / h;             // 1024
  const int batch = in_sizes[0] / (n * d);   // 256
  const int S = 7;                           // fine_steps-1
  const int MAXIT = 2;
  const size_t NB = (size_t)batch * d;

  float* Bw = (float*)d_out;

  uint8_t* wsb = (uint8_t*)d_ws;
  size_t off = 0;
  auto carve = [&](size_t bytes) -> void* {
    off = (off + 255) & ~(size_t)255;
    void* p = wsb + off; off += bytes; return p;
  };

  const size_t WH = (size_t)d * h;
  unsigned short* W1Th = (unsigned short*)carve(WH * 2);
  unsigned short* W1Tl = (unsigned short*)carve(WH * 2);
  unsigned short* W2Th = (unsigned short*)carve(WH * 2);
  unsigned short* W2Tl = (unsigned short*)carve(WH * 2);
  float* Dbuf = (float*)carve((size_t)(n - 1) * NB * 4);
  float* Eb   = (float*)carve((size_t)n * NB * 4);

  const int SPL2 = 4;
  float* Part = (float*)carve((size_t)SPL2 * NB * 4);

  // per node (Cst deleted; coarse state lives in Dbuf slot):
  // Xf(4) + Xh(2) + Xl(2) + ACC(4) + Csh/XT(2) + Csl/XT(2) = 16 B/elem
  // + Yh/Yl = 4 B/elem over batch*h
  const size_t per_node = NB * 16 + (size_t)batch * h * 4;
  int c;
  {
    size_t remb = ws_size > off + (1u << 20) ? ws_size - off - (1u << 20) : 0;
    c = (int)(remb / per_node);
    if (c < 1) c = 1;
    if (c > n - 1) c = n - 1;
  }
  const size_t CE = (size_t)c * NB;
  unsigned short* Csh = (unsigned short*)carve(CE * 2);
  unsigned short* Csl = (unsigned short*)carve(CE * 2);
  float*          Xf  = (float*)carve(CE * 4);
  unsigned short* Xh  = (unsigned short*)carve(CE * 2);
  unsigned short* Xl  = (unsigned short*)carve(CE * 2);
  float*          ACC = (float*)carve(CE * 4);
  unsigned short* Yh  = (unsigned short*)carve((size_t)c * batch * h * 2);
  unsigned short* Yl  = (unsigned short*)carve((size_t)c * batch * h * 2);
  unsigned short* XTh = Csh;   // time-disjoint with coarse sweep
  unsigned short* XTl = Csl;

  auto pickst = [](int g, int want) {
    int s = want;
    while (s > 1 && (g % s)) s >>= 1;
    return s;
  };
  auto ewg = [](size_t n4) -> int {
    size_t g = (n4 + 255) / 256;
    if (g > 2048) g = 2048; if (g < 1) g = 1;
    return (int)g;
  };
  auto axpy = [&](float* dF, unsigned short* dH, unsigned short* dL,
                  const float* A, const float* Fv, float coef, size_t ne) {
    const int n4 = (int)(ne / 4);
    axpy_split_k<<<ewg(n4), 256, 0, stream>>>(dF, dH, dL, A, Fv, coef, n4);
  };
  auto g1 = [&](const unsigned short* xh, const unsigned short* xl, int M) {
    const int gy = M / 128;
    gemm_k<1><<<dim3(h / 128, gy, 1), 256, 0, stream>>>(
        xh, xl, W1Th, W1Tl, b1, Yh, Yl,
        nullptr, nullptr, nullptr, tspan, 0.f, 0.f, 0, M, h, d, d,
        pickst(h / 128, 8), pickst(gy, 4));
  };
  auto g2rk = [&](int M, float a1, float a2, int add) {
    const int gy = M / 128;
    gemm_k<3><<<dim3(d / 128, gy, 1), 256, 0, stream>>>(
        Yh, Yl, W2Th, W2Tl, nullptr, XTh, XTl,
        Xf, ACC, nullptr, tspan, a1, a2, add, M, d, h, h,
        pickst(d / 128, 4), pickst(gy, 4));
  };
  auto g2ax = [&](int M, float* dF, unsigned short* dH, unsigned short* dL,
                  const float* Xin, float a1, float a2) {
    const int gy = M / 128;
    gemm_k<4><<<dim3(d / 128, gy, 1), 256, 0, stream>>>(
        Yh, Yl, W2Th, W2Tl, nullptr, dH, dL,
        Xin, nullptr, dF, tspan, a1, a2, 0, M, d, h, h,
        pickst(d / 128, 4), pickst(gy, 4));
  };

  // ---- prep ---------------------------------------------------------------
  hipMemcpyAsync(Bw, Bin, (size_t)n * NB * 4, hipMemcpyDeviceToDevice, stream);
  transpose_split_k<<<dim3(h / 32, d / 32), 256, 0, stream>>>(W1, W1Th, W1Tl, d, h);
  transpose_split_k<<<dim3(d / 32, h / 32), 256, 0, stream>>>(W2, W2Th, W2Tl, h, d);

  const int MN4d = (int)(NB / 4);

  // ---- Parareal outer loop ------------------------------------------------
  for (int i = 1; i <= MAXIT + 1; ++i) {
    const int rem = n - i;

    for (int base = 0; base < rem; base += c) {
      const int cc = (rem - base) < c ? (rem - base) : c;
      const int M = cc * batch;
      const size_t ne = (size_t)M * d;
      const int j0 = i - 1 + base;
      const float* src = Bw + (size_t)j0 * NB;
      float* Dslot = Dbuf + (size_t)base * NB;

      if (i == 1) {
        // coarse Euler sweep; state lives directly in Dslot (R4 pattern)
        axpy(Dslot, Csh, Csl, src, src, 0.f, ne);
        for (int s = 0; s < S; ++s) {
          g1(Csh, Csl, M);
          g2ax(M, Dslot, Csh, Csl, Dslot, 0.f, 1.f);
        }
      }
      // fine RK4 sweep
      axpy(Xf, Xh, Xl, src, src, 0.f, ne);
      for (int s = 0; s < S; ++s) {
        g1(Xh, Xl, M);   g2rk(M, 1.f / 6.f, 0.5f, 0);   // k1
        g1(XTh, XTl, M); g2rk(M, 1.f / 3.f, 0.5f, 1);   // k2
        g1(XTh, XTl, M); g2rk(M, 1.f / 3.f, 1.0f, 1);   // k3
        g1(XTh, XTl, M); g2ax(M, Xf, Xh, Xl, ACC, 0.f, 1.f / 6.f);  // k4
      }
      // D = fine - coarse (coarse for i==1 is in Dslot; i>=2 uses Eb)
      const float* Cref = (i == 1) ? Dslot : (Eb + (size_t)j0 * NB);
      axpy(Dslot, nullptr, nullptr, Xf, Cref, -1.f, ne);
    }

    // ---- sequential Parareal correction: 3 dispatches/substep, 64^2 -------
    const float* start = Bw + (size_t)(i - 1) * NB;
    axpy(Xf, Xh, Xl, start, start, 0.f, NB);
    for (int m = 0; m < rem; ++m) {
      for (int s = 0; s < S; ++s) {
        gemm64_k<1><<<dim3(h / 64, batch / 64, 1), 256, 0, stream>>>(
            Xh, Xl, W1Th, W1Tl, b1, nullptr, Yh, Yl, batch, h, d, d,
            pickst(h / 64, 8), pickst(batch / 64, 4));
        gemm64_k<2><<<dim3(d / 64, batch / 64, SPL2), 256, 0, stream>>>(
            Yh, Yl, W2Th, W2Tl, nullptr, Part, nullptr, nullptr,
            batch, d, h, h / SPL2,
            pickst(d / 64, 8), pickst(batch / 64, 4));
        const bool last = (s == S - 1);
        reduce_axpy_k<<<(MN4d + 255) / 256, 256, 0, stream>>>(
            Part, SPL2, MN4d, tspan, Xf, Xh, Xl,
            last ? Dbuf + (size_t)m * NB : nullptr,
            last ? Bw + (size_t)(i + m) * NB : nullptr,
            last ? Eb + (size_t)(i - 1 + m) * NB : nullptr);
      }
    }
  }
}